// Round 15
// baseline (831.681 us; speedup 1.0000x reference)
//
#include <hip/hip_runtime.h>
#include <hip/hip_bf16.h>

using bf16x8 = __attribute__((ext_vector_type(8))) __bf16;
using f32x4  = __attribute__((ext_vector_type(4))) float;

constexpr int Bc = 2, Sc = 2048, Dc = 2048, HQc = 16, HKVc = 4, HDc = 128, FFc = 8192;

__device__ __forceinline__ void gload16(const void* g, void* l) {
  __builtin_amdgcn_global_load_lds((const __attribute__((address_space(1))) void*)g,
                                   (__attribute__((address_space(3))) void*)l, 16, 0, 0);
}

// ---------------- transpose-cast: fp32 [R,C] -> bf16 [C,R] ----------------
__global__ __launch_bounds__(256) void wtrans_kernel(const float* __restrict__ in,
                                                     __bf16* __restrict__ out,
                                                     int R, int C) {
  __shared__ float tile[32][33];
  const int tx = threadIdx.x, ty = threadIdx.y;
  const int c0 = blockIdx.x * 32, r0 = blockIdx.y * 32;
#pragma unroll
  for (int i = 0; i < 4; ++i)
    tile[ty + 8 * i][tx] = in[(size_t)(r0 + ty + 8 * i) * C + (c0 + tx)];
  __syncthreads();
#pragma unroll
  for (int i = 0; i < 4; ++i)
    out[(size_t)(c0 + ty + 8 * i) * R + (r0 + tx)] = (__bf16)tile[tx][ty + 8 * i];
}

// ---------------- V slice [.,stride] bf16 -> Vt [B,G,HD,S] bf16 ----------------
__global__ __launch_bounds__(256) void vtrans_kernel(const __bf16* __restrict__ V,
                                                     __bf16* __restrict__ Vt, int stride) {
  __shared__ __bf16 tile[32][33];
  const int tx = threadIdx.x, ty = threadIdx.y;
  const int s0 = blockIdx.x * 32, c0 = blockIdx.y * 32, b = blockIdx.z;
#pragma unroll
  for (int i = 0; i < 4; ++i)
    tile[ty + 8 * i][tx] = V[(size_t)(b * Sc + s0 + ty + 8 * i) * stride + c0 + tx];
  __syncthreads();
#pragma unroll
  for (int i = 0; i < 4; ++i) {
    const int c = c0 + ty + 8 * i;
    Vt[((size_t)(b * HKVc + (c >> 7)) * HDc + (c & 127)) * Sc + s0 + tx] = tile[tx][ty + 8 * i];
  }
}

// ---------------- RMSNorm: fp32 [rows, 2048] -> bf16 ----------------
__global__ __launch_bounds__(256) void rmsnorm_kernel(const float* __restrict__ x,
                                                      const float* __restrict__ w,
                                                      __bf16* __restrict__ out) {
  const int row = blockIdx.x;
  const int t = threadIdx.x;
  const float* xr = x + (size_t)row * Dc + t * 8;
  float4 v0 = *(const float4*)(xr);
  float4 v1 = *(const float4*)(xr + 4);
  float ss = v0.x * v0.x + v0.y * v0.y + v0.z * v0.z + v0.w * v0.w +
             v1.x * v1.x + v1.y * v1.y + v1.z * v1.z + v1.w * v1.w;
#pragma unroll
  for (int off = 32; off > 0; off >>= 1) ss += __shfl_down(ss, off);
  __shared__ float wsum[4];
  if ((t & 63) == 0) wsum[t >> 6] = ss;
  __syncthreads();
  const float tot = wsum[0] + wsum[1] + wsum[2] + wsum[3];
  const float scale = rsqrtf(tot * (1.0f / Dc) + 1e-6f);
  const float* wp = w + t * 8;
  bf16x8 o;
  o[0] = (__bf16)(v0.x * scale * wp[0]);
  o[1] = (__bf16)(v0.y * scale * wp[1]);
  o[2] = (__bf16)(v0.z * scale * wp[2]);
  o[3] = (__bf16)(v0.w * scale * wp[3]);
  o[4] = (__bf16)(v1.x * scale * wp[4]);
  o[5] = (__bf16)(v1.y * scale * wp[5]);
  o[6] = (__bf16)(v1.z * scale * wp[6]);
  o[7] = (__bf16)(v1.w * scale * wp[7]);
  *(bf16x8*)(out + (size_t)row * Dc + t * 8) = o;
}

// ---------------- split-K reduce: out = p0 + p1 + res + bias[col] ----------------
__global__ __launch_bounds__(256) void reduce_out_kernel(const float* __restrict__ p0,
                                                         const float* __restrict__ p1,
                                                         const float* __restrict__ res,
                                                         const float* __restrict__ bias,
                                                         float* __restrict__ out) {
  const size_t i = ((size_t)blockIdx.x * 256 + threadIdx.x) * 4;
  const int col = (int)(i & 2047);
  float4 a = *(const float4*)(p0 + i);
  float4 b = *(const float4*)(p1 + i);
  float4 r = *(const float4*)(res + i);
  float4 bs = *(const float4*)(bias + col);
  float4 o;
  o.x = a.x + b.x + r.x + bs.x;
  o.y = a.y + b.y + r.y + bs.y;
  o.z = a.z + b.z + r.z + bs.z;
  o.w = a.w + b.w + r.w + bs.w;
  *(float4*)(out + i) = o;
}

// ---------------- GEMM 256x256, 2-phase/K-tile (merged), counted vmcnt ----------------
// r15: phases merged pairwise — 32-MFMA clusters, 4 barriers/K-tile (was 8).
// Row-major flatten + XCD swizzle. T2 swizzle (conflicts=0).
// EP: 0 bf16; 1 fp32+res; 5 fp32 partial at Cout + z*M*N (split-K)
template <int EP>
__global__ __launch_bounds__(512, 2) void gemm256(
    const __bf16* __restrict__ A, const __bf16* __restrict__ Bt,
    void* __restrict__ Cout, int M, int N, int K, int lda,
    const float* __restrict__ res, const float* __restrict__ bias,
    const __bf16* aux) {
  __shared__ __attribute__((aligned(16))) __bf16 lds[65536];
  const int tid = threadIdx.x;
  const int l = tid & 63, w = tid >> 6;
  const int lm = l & 15, lh = l >> 4;
  const int wr = w >> 2, wc = w & 3;

  int wg = blockIdx.y * gridDim.x + blockIdx.x;
  const int nwg = gridDim.x * gridDim.y;
  wg = (wg & 7) * (nwg >> 3) + (wg >> 3);
  const int bm = (wg / gridDim.x) * 256, bn = (wg % gridDim.x) * 256;
  const int kz = blockIdx.z;

  f32x4 acc[8][4] = {};

  const int srow = w * 16 + (l >> 2);
  const int scol = (((l & 3) ^ ((l >> 3) & 3))) * 8;
  const __bf16* abase = A + (size_t)(bm + srow) * lda + kz * K + scol;
  const __bf16* bbase = Bt + (size_t)(bn + srow) * lda + kz * K + scol;
  const size_t j1 = (size_t)128 * lda;
  const int sdst = w * 512;

  const int xsw = (lm >> 1) & 3;
  const int aoff = (wr * 128 + lm) * 32 + (lh ^ xsw) * 8;
  const int boff = (wc * 64 + lm) * 32 + (lh ^ xsw) * 8;
  const int NT = K >> 6;

  gload16(abase, &lds[sdst]);
  gload16(abase + j1, &lds[4096 + sdst]);
  gload16(bbase, &lds[32768 + sdst]);
  gload16(bbase + j1, &lds[32768 + 4096 + sdst]);
  gload16(abase + 32, &lds[8192 + sdst]);
  gload16(abase + 32 + j1, &lds[8192 + 4096 + sdst]);
  gload16(bbase + 32, &lds[32768 + 8192 + sdst]);
  gload16(bbase + 32 + j1, &lds[32768 + 8192 + 4096 + sdst]);
  gload16(abase + 64, &lds[16384 + sdst]);
  gload16(abase + 64 + j1, &lds[16384 + 4096 + sdst]);
  gload16(bbase + 64, &lds[32768 + 16384 + sdst]);
  gload16(bbase + 64 + j1, &lds[32768 + 16384 + 4096 + sdst]);
  asm volatile("s_waitcnt vmcnt(4)" ::: "memory");
  __builtin_amdgcn_s_barrier();
  __builtin_amdgcn_sched_barrier(0);

  for (int t = 0; t < NT; ++t) {
    const int pb = (t & 1) * 16384;
    const int qb = 16384 - pb;

    {  // phase 0: ks=0, all m (af[8], 32 MFMA)
      bf16x8 af[8], bq[4];
#pragma unroll
      for (int i = 0; i < 4; ++i) af[i] = *(const bf16x8*)&lds[pb + aoff + i * 512];
#pragma unroll
      for (int i = 0; i < 4; ++i) af[i + 4] = *(const bf16x8*)&lds[pb + aoff + 2048 + i * 512];
#pragma unroll
      for (int n = 0; n < 4; ++n) bq[n] = *(const bf16x8*)&lds[32768 + pb + boff + n * 512];
      if (t + 1 < NT) {  // stage A-k1(t+1), B-k1(t+1)
        const __bf16* sa = abase + (size_t)(t + 1) * 64 + 32;
        const __bf16* sb = bbase + (size_t)(t + 1) * 64 + 32;
        gload16(sa, &lds[qb + 8192 + sdst]);
        gload16(sa + j1, &lds[qb + 8192 + 4096 + sdst]);
        gload16(sb, &lds[32768 + qb + 8192 + sdst]);
        gload16(sb + j1, &lds[32768 + qb + 8192 + 4096 + sdst]);
      }
      __builtin_amdgcn_s_barrier();
      __builtin_amdgcn_s_setprio(1);
#pragma unroll
      for (int m = 0; m < 8; ++m)
#pragma unroll
        for (int n = 0; n < 4; ++n)
          acc[m][n] = __builtin_amdgcn_mfma_f32_16x16x32_bf16(af[m], bq[n], acc[m][n], 0, 0, 0);
      __builtin_amdgcn_s_setprio(0);
      __builtin_amdgcn_s_barrier();
    }
    {  // phase 1: ks=1, all m (+ K-tile boundary vmcnt)
      bf16x8 af[8], bq[4];
#pragma unroll
      for (int i = 0; i < 4; ++i) af[i] = *(const bf16x8*)&lds[pb + 8192 + aoff + i * 512];
#pragma unroll
      for (int i = 0; i < 4; ++i)
        af[i + 4] = *(const bf16x8*)&lds[pb + 8192 + aoff + 2048 + i * 512];
#pragma unroll
      for (int n = 0; n < 4; ++n) bq[n] = *(const bf16x8*)&lds[32768 + pb + 8192 + boff + n * 512];
      if (t + 2 < NT) {  // stage A-k0(t+2), B-k0(t+2)
        const __bf16* sa = abase + (size_t)(t + 2) * 64;
        const __bf16* sb = bbase + (size_t)(t + 2) * 64;
        gload16(sa, &lds[pb + sdst]);
        gload16(sa + j1, &lds[pb + 4096 + sdst]);
        gload16(sb, &lds[32768 + pb + sdst]);
        gload16(sb + j1, &lds[32768 + pb + 4096 + sdst]);
        asm volatile("s_waitcnt vmcnt(4)" ::: "memory");
      } else {
        asm volatile("s_waitcnt vmcnt(0)" ::: "memory");
      }
      __builtin_amdgcn_sched_barrier(0);
      __builtin_amdgcn_s_barrier();
      __builtin_amdgcn_s_setprio(1);
#pragma unroll
      for (int m = 0; m < 8; ++m)
#pragma unroll
        for (int n = 0; n < 4; ++n)
          acc[m][n] = __builtin_amdgcn_mfma_f32_16x16x32_bf16(af[m], bq[n], acc[m][n], 0, 0, 0);
      __builtin_amdgcn_s_setprio(0);
      __builtin_amdgcn_s_barrier();
    }
  }

#pragma unroll
  for (int m = 0; m < 8; ++m) {
#pragma unroll
    for (int n = 0; n < 4; ++n) {
#pragma unroll
      for (int r = 0; r < 4; ++r) {
        const int row = bm + wr * 128 + m * 16 + lh * 4 + r;
        const int col = bn + wc * 64 + n * 16 + lm;
        const size_t idx = (size_t)row * N + col;
        const float v = acc[m][n][r];
        if constexpr (EP == 0) {
          ((__bf16*)Cout)[idx] = (__bf16)v;
        } else if constexpr (EP == 1) {
          ((float*)Cout)[idx] = v + res[idx];
        } else {
          ((float*)Cout)[(size_t)kz * M * N + idx] = v;
        }
      }
    }
  }
}

// ---------------- Fused FFN: H = silu(A@Bl^T + lb) * (A@Bg^T + gb) ----------------
// r14: 2-col interleave (FETCH 1.07GB -> 556MB). r15: merged phases — 32-MFMA
// clusters, 4 barriers/K-tile (was 8). LDS 144KB; T2 swizzle; counted vmcnt(4).
__global__ __launch_bounds__(512, 2) void gemmffn(
    const __bf16* __restrict__ A, const __bf16* __restrict__ Bg,
    const __bf16* __restrict__ Bl, __bf16* __restrict__ H,
    const float* __restrict__ gb, const float* __restrict__ lb) {
  __shared__ __attribute__((aligned(16))) __bf16 lds[73728];
  const int tid = threadIdx.x;
  const int l = tid & 63, w = tid >> 6;
  const int lm = l & 15, lh = l >> 4;
  const int wr = w >> 2, wc = w & 3;

  // col-major flatten + XCD swizzle + 2-col interleave within chunk (bijective)
  int wg = blockIdx.x * 32 + blockIdx.y;       // c*32 + m
  wg = (wg & 7) * 128 + (wg >> 3);             // XCD chunk of 128
  const int chunk = wg >> 7;                   // 0..7
  const int within = wg & 127;
  const int cp = within >> 6;                  // col-pair within chunk (0/1)
  const int r2 = within & 63;
  const int bm = (r2 >> 1) * 128;              // m = 0..31
  const int bn = (chunk * 4 + cp * 2 + (r2 & 1)) * 256;

  f32x4 ag[4][4] = {}, al[4][4] = {};

  const int srA = tid >> 2;
  const int scA = ((tid & 3) ^ ((tid >> 3) & 3)) * 8;
  const __bf16* abase = A + (size_t)(bm + srA) * 2048 + scA;
  const int srB = w * 16 + (l >> 2);
  const int scB = (((l & 3) ^ ((l >> 3) & 3))) * 8;
  const __bf16* gbase = Bg + (size_t)(bn + srB) * 2048 + scB;
  const __bf16* lbase = Bl + (size_t)(bn + srB) * 2048 + scB;
  const size_t j1 = (size_t)128 * 2048;
  const int sdst = w * 512;

  const int xsw = (lm >> 1) & 3;
  const int aro = (wr * 64 + lm) * 32 + (lh ^ xsw) * 8;
  const int bro = (wc * 64 + lm) * 32 + (lh ^ xsw) * 8;
  const int NT = 32;  // K=2048 / 64
  // LDS bases: A kh0=0, kh1=4096; Bg = 8192 + d*16384 + kh*8192; Bl = 40960 + ...

  // ---- prologue ----
  gload16(abase, &lds[sdst]);
  gload16(abase + 32, &lds[4096 + sdst]);
  gload16(gbase, &lds[8192 + sdst]);
  gload16(gbase + j1, &lds[8192 + 4096 + sdst]);
  gload16(gbase + 32, &lds[8192 + 8192 + sdst]);
  gload16(gbase + 32 + j1, &lds[8192 + 8192 + 4096 + sdst]);
  gload16(lbase, &lds[40960 + sdst]);
  gload16(lbase + j1, &lds[40960 + 4096 + sdst]);
  gload16(lbase + 32, &lds[40960 + 8192 + sdst]);
  gload16(lbase + 32 + j1, &lds[40960 + 8192 + 4096 + sdst]);
  gload16(gbase + 64, &lds[8192 + 16384 + sdst]);
  gload16(gbase + 64 + j1, &lds[8192 + 16384 + 4096 + sdst]);
  gload16(lbase + 64, &lds[40960 + 16384 + sdst]);
  gload16(lbase + 64 + j1, &lds[40960 + 16384 + 4096 + sdst]);
  asm volatile("s_waitcnt vmcnt(4)" ::: "memory");
  __builtin_amdgcn_s_barrier();
  __builtin_amdgcn_sched_barrier(0);

  for (int t = 0; t < NT; ++t) {
    const int gB = 8192 + (t & 1) * 16384;
    const int lB = 40960 + (t & 1) * 16384;
    const int gBn = 8192 + 16384 - (t & 1) * 16384;
    const int lBn = 40960 + 16384 - (t & 1) * 16384;

    bf16x8 a0[4], a1[4], bgq[4], blq[4];
    {  // phase 0 (kh0): A both halves + Bg/Bl kh0; stage Bg/Bl-k1(t+1); 32 MFMA
#pragma unroll
      for (int i = 0; i < 4; ++i) a0[i] = *(const bf16x8*)&lds[aro + i * 512];
#pragma unroll
      for (int i = 0; i < 4; ++i) a1[i] = *(const bf16x8*)&lds[4096 + aro + i * 512];
#pragma unroll
      for (int n = 0; n < 4; ++n) bgq[n] = *(const bf16x8*)&lds[gB + bro + n * 512];
#pragma unroll
      for (int n = 0; n < 4; ++n) blq[n] = *(const bf16x8*)&lds[lB + bro + n * 512];
      if (t + 1 < NT) {
        const __bf16* sg = gbase + (size_t)(t + 1) * 64 + 32;
        const __bf16* sl = lbase + (size_t)(t + 1) * 64 + 32;
        gload16(sg, &lds[gBn + 8192 + sdst]);
        gload16(sg + j1, &lds[gBn + 8192 + 4096 + sdst]);
        gload16(sl, &lds[lBn + 8192 + sdst]);
        gload16(sl + j1, &lds[lBn + 8192 + 4096 + sdst]);
      }
      __builtin_amdgcn_s_barrier();
      __builtin_amdgcn_s_setprio(1);
#pragma unroll
      for (int m = 0; m < 4; ++m)
#pragma unroll
        for (int n = 0; n < 4; ++n)
          ag[m][n] = __builtin_amdgcn_mfma_f32_16x16x32_bf16(a0[m], bgq[n], ag[m][n], 0, 0, 0);
#pragma unroll
      for (int m = 0; m < 4; ++m)
#pragma unroll
        for (int n = 0; n < 4; ++n)
          al[m][n] = __builtin_amdgcn_mfma_f32_16x16x32_bf16(a0[m], blq[n], al[m][n], 0, 0, 0);
      __builtin_amdgcn_s_setprio(0);
      __builtin_amdgcn_s_barrier();
    }
    {  // phase 1 (kh1): Bg/Bl kh1; stage A(t+1) + Bg/Bl-k0(t+2); vmcnt; 32 MFMA
#pragma unroll
      for (int n = 0; n < 4; ++n) bgq[n] = *(const bf16x8*)&lds[gB + 8192 + bro + n * 512];
#pragma unroll
      for (int n = 0; n < 4; ++n) blq[n] = *(const bf16x8*)&lds[lB + 8192 + bro + n * 512];
      if (t + 1 < NT) {
        const __bf16* sa = abase + (size_t)(t + 1) * 64;
        gload16(sa, &lds[sdst]);
        gload16(sa + 32, &lds[4096 + sdst]);
      }
      if (t + 2 < NT) {
        const __bf16* sg = gbase + (size_t)(t + 2) * 64;
        const __bf16* sl = lbase + (size_t)(t + 2) * 64;
        gload16(sg, &lds[gB + sdst]);
        gload16(sg + j1, &lds[gB + 4096 + sdst]);
        gload16(sl, &lds[lB + sdst]);
        gload16(sl + j1, &lds[lB + 4096 + sdst]);
        asm volatile("s_waitcnt vmcnt(4)" ::: "memory");
      } else {
        asm volatile("s_waitcnt vmcnt(0)" ::: "memory");
      }
      __builtin_amdgcn_sched_barrier(0);
      __builtin_amdgcn_s_barrier();
      __builtin_amdgcn_s_setprio(1);
#pragma unroll
      for (int m = 0; m < 4; ++m)
#pragma unroll
        for (int n = 0; n < 4; ++n)
          ag[m][n] = __builtin_amdgcn_mfma_f32_16x16x32_bf16(a1[m], bgq[n], ag[m][n], 0, 0, 0);
#pragma unroll
      for (int m = 0; m < 4; ++m)
#pragma unroll
        for (int n = 0; n < 4; ++n)
          al[m][n] = __builtin_amdgcn_mfma_f32_16x16x32_bf16(a1[m], blq[n], al[m][n], 0, 0, 0);
      __builtin_amdgcn_s_setprio(0);
      __builtin_amdgcn_s_barrier();
    }
  }

#pragma unroll
  for (int m = 0; m < 4; ++m) {
#pragma unroll
    for (int n = 0; n < 4; ++n) {
#pragma unroll
      for (int r = 0; r < 4; ++r) {
        const int row = bm + wr * 64 + m * 16 + lh * 4 + r;
        const int col = bn + wc * 64 + n * 16 + lm;
        const float g = ag[m][n][r] + gb[col];
        const float li = al[m][n][r] + lb[col];
        const float sil = li / (1.0f + __expf(-li));
        H[(size_t)row * 8192 + col] = (__bf16)(sil * g);
      }
    }
  }
}

// ---------------- Flash attention, causal + learned additive bias ----------------
// QBLK=128, 512 thr / 8 waves; complementary qtile pairing for balance.
__global__ __launch_bounds__(512) void attn_kernel(
    const __bf16* __restrict__ QKV, const __bf16* __restrict__ Vt,
    const float* __restrict__ pbias, __bf16* __restrict__ O) {
  __shared__ __bf16 klds[64][136];
  __shared__ __bf16 vlds[128][72];
  __shared__ __bf16 plds[8][16][72];
  const int tid = threadIdx.x;
  const int w = tid >> 6, l = tid & 63;
  const int lm = l & 15, lh = l >> 4;
  const int by = blockIdx.x;
  const int b = by >> 4, h = by & 15;
  const int g = h >> 2;
  const int qy = blockIdx.y;
  const int qt = (qy < 8) ? qy : (23 - qy);
  const int q0b = qt * 128;
  const int q0 = q0b + w * 16;

  bf16x8 qf[4];
  {
    const __bf16* qbase = QKV + (size_t)(b * Sc + q0 + lm) * 3072 + h * HDc + lh * 8;
#pragma unroll
    for (int ks = 0; ks < 4; ++ks) qf[ks] = *(const bf16x8*)(qbase + ks * 32);
  }

  f32x4 oacc[8] = {};
  float mrow[4] = {-3e38f, -3e38f, -3e38f, -3e38f};
  float lrow[4] = {0.f, 0.f, 0.f, 0.f};
  const float sc_qk = 0.088388347648318447f;

  const __bf16* kgb = QKV + (size_t)b * Sc * 3072 + 2048 + g * 128;
  const __bf16* vgb = Vt + (size_t)(b * HKVc + g) * HDc * Sc;
  const float* pgb = pbias + (size_t)h * Sc * Sc;

  const int skr = tid >> 4;
  const int skc = (tid & 15) * 8;
  const int svr = tid >> 3;
  const int svc = (tid & 7) * 8;

  bf16x8 kreg[2], vreg[2];
  float breg[4][4];

  {
#pragma unroll
    for (int i = 0; i < 2; ++i)
      kreg[i] = *(const bf16x8*)(kgb + (size_t)(i * 32 + skr) * 3072 + skc);
#pragma unroll
    for (int i = 0; i < 2; ++i)
      vreg[i] = *(const bf16x8*)(vgb + (size_t)(i * 64 + svr) * Sc + svc);
#pragma unroll
    for (int c = 0; c < 4; ++c)
#pragma unroll
      for (int r = 0; r < 4; ++r)
        breg[c][r] = pgb[(size_t)(q0 + lh * 4 + r) * Sc + c * 16 + lm];
  }

  const int nt = 2 * qt + 2;
  for (int t = 0; t < nt; ++t) {
    const int kv0 = t * 64;
    __syncthreads();
#pragma unroll
    for (int i = 0; i < 2; ++i) *(bf16x8*)&klds[i * 32 + skr][skc] = kreg[i];
#pragma unroll
    for (int i = 0; i < 2; ++i) *(bf16x8*)&vlds[i * 64 + svr][svc] = vreg[i];
    __syncthreads();

    if (t + 1 < nt) {
      const int nv0 = kv0 + 64;
#pragma unroll
      for (int i = 0; i < 2; ++i)
        kreg[i] = *(const bf16x8*)(kgb + (size_t)(nv0 + i * 32 + skr) * 3072 + skc);
#pragma unroll
      for (int i = 0; i < 2; ++i)
        vreg[i] = *(const bf16x8*)(vgb + (size_t)(i * 64 + svr) * Sc + nv0 + svc);
    }

    float sv[4][4];
#pragma unroll
    for (int c = 0; c < 4; ++c) {
      f32x4 acc = {};
#pragma unroll
      for (int ks = 0; ks < 4; ++ks) {
        bf16x8 kf = *(const bf16x8*)&klds[c * 16 + lm][ks * 32 + lh * 8];
        acc = __builtin_amdgcn_mfma_f32_16x16x32_bf16(qf[ks], kf, acc, 0, 0, 0);
      }
      const int kvg = kv0 + c * 16 + lm;
#pragma unroll
      for (int r = 0; r < 4; ++r) {
        const int qg = q0 + lh * 4 + r;
        sv[c][r] = (kvg <= qg) ? (acc[r] * sc_qk + breg[c][r]) : -1e9f;
      }
    }

    if (t + 1 < nt) {
      const int nv0 = kv0 + 64;
#pragma unroll
      for (int c = 0; c < 4; ++c)
#pragma unroll
        for (int r = 0; r < 4; ++r)
          breg[c][r] = pgb[(size_t)(q0 + lh * 4 + r) * Sc + nv0 + c * 16 + lm];
    }

    float tmv[4];
    bool needb = false;
#pragma unroll
    for (int r = 0; r < 4; ++r) {
      float tm = fmaxf(fmaxf(sv[0][r], sv[1][r]), fmaxf(sv[2][r], sv[3][r]));
      tm = fmaxf(tm, __shfl_xor(tm, 1));
      tm = fmaxf(tm, __shfl_xor(tm, 2));
      tm = fmaxf(tm, __shfl_xor(tm, 4));
      tm = fmaxf(tm, __shfl_xor(tm, 8));
      tmv[r] = tm;
      needb = needb || (tm > mrow[r] + 8.0f);
    }
    if (__any(needb)) {
#pragma unroll
      for (int r = 0; r < 4; ++r) {
        const float mn = fmaxf(mrow[r], tmv[r]);
        const float fac = __expf(mrow[r] - mn);
        mrow[r] = mn;
        lrow[r] *= fac;
#pragma unroll
        for (int d0 = 0; d0 < 8; ++d0) oacc[d0][r] *= fac;
      }
    }
    float pv[4][4];
#pragma unroll
    for (int r = 0; r < 4; ++r) {
      float rs = 0.f;
#pragma unroll
      for (int c = 0; c < 4; ++c) {
        pv[c][r] = __expf(sv[c][r] - mrow[r]);
        rs += pv[c][r];
      }
      rs += __shfl_xor(rs, 1);
      rs += __shfl_xor(rs, 2);
      rs += __shfl_xor(rs, 4);
      rs += __shfl_xor(rs, 8);
      lrow[r] += rs;
    }

#pragma unroll
    for (int c = 0; c < 4; ++c)
#pragma unroll
      for (int r = 0; r < 4; ++r)
        plds[w][lh * 4 + r][c * 16 + lm] = (__bf16)pv[c][r];
    asm volatile("s_waitcnt lgkmcnt(0)" ::: "memory");
    __builtin_amdgcn_sched_barrier(0);
    bf16x8 pa0 = *(const bf16x8*)&plds[w][lm][lh * 8];
    bf16x8 pa1 = *(const bf16x8*)&plds[w][lm][32 + lh * 8];
#pragma unroll
    for (int d0 = 0; d0 < 8; ++d0) {
      bf16x8 vf0 = *(const bf16x8*)&vlds[d0 * 16 + lm][lh * 8];
      bf16x8 vf1 = *(const bf16x8*)&vlds[d0 * 16 + lm][32 + lh * 8];
      oacc[d0] = __builtin_amdgcn_mfma_f32_16x16x32_bf16(pa0, vf0, oacc[d0], 0, 0, 0);
      oacc[d0] = __builtin_amdgcn_mfma_f32_16x16x32_bf16(pa1, vf1, oacc[d0], 0, 0, 0);
    }
  }

  __syncthreads();
  if (w < 4) {
#pragma unroll
    for (int r = 0; r < 4; ++r) {
      const float inv = 1.0f / lrow[r];
#pragma unroll
      for (int d0 = 0; d0 < 8; ++d0)
        klds[w * 16 + lh * 4 + r][d0 * 16 + lm] = (__bf16)(oacc[d0][r] * inv);
    }
    asm volatile("s_waitcnt lgkmcnt(0)" ::: "memory");
    __builtin_amdgcn_sched_barrier(0);
    __bf16* ob = O + ((size_t)(b * Sc + q0 + lm) * HQc + h) * HDc;
#pragma unroll
    for (int c = 0; c < 4; ++c)
      *(bf16x8*)(ob + (c * 4 + lh) * 8) = *(const bf16x8*)&klds[w * 16 + lm][(c * 4 + lh) * 8];
  }
  __syncthreads();
  if (w >= 4) {
    const int wl = w - 4;
#pragma unroll
    for (int r = 0; r < 4; ++r) {
      const float inv = 1.0f / lrow[r];
#pragma unroll
      for (int d0 = 0; d0 < 8; ++d0)
        klds[wl * 16 + lh * 4 + r][d0 * 16 + lm] = (__bf16)(oacc[d0][r] * inv);
    }
    asm volatile("s_waitcnt lgkmcnt(0)" ::: "memory");
    __builtin_amdgcn_sched_barrier(0);
    __bf16* ob = O + ((size_t)(b * Sc + q0 + lm) * HQc + h) * HDc;
#pragma unroll
    for (int c = 0; c < 4; ++c)
      *(bf16x8*)(ob + (c * 4 + lh) * 8) = *(const bf16x8*)&klds[wl * 16 + lm][(c * 4 + lh) * 8];
  }
}

extern "C" void kernel_launch(void* const* d_in, const int* in_sizes, int n_in,
                              void* d_out, int out_size, void* d_ws, size_t ws_size,
                              hipStream_t stream) {
  const float* x = (const float*)d_in[0];
  // d_in[1] = causal mask, applied analytically
  const float* pbias = (const float*)d_in[2];
  const float* wq = (const float*)d_in[3];
  const float* wk = (const float*)d_in[4];
  const float* wv = (const float*)d_in[5];
  const float* wo = (const float*)d_in[6];
  const float* attn_norm_w = (const float*)d_in[7];
  const float* linear_norm_w = (const float*)d_in[8];
  const float* gate_w = (const float*)d_in[9];
  const float* gate_b = (const float*)d_in[10];
  const float* lin_w = (const float*)d_in[11];
  const float* lin_b = (const float*)d_in[12];
  const float* out_w = (const float*)d_in[13];
  const float* out_b = (const float*)d_in[14];

  if (ws_size < 335544320) return;  // layout below needs 320 MB

  char* ws = (char*)d_ws;
  __bf16* wqkvt = (__bf16*)(ws + 0);          // [3072,2048]: wq^T, wk^T, wv^T stacked
  __bf16* wot = (__bf16*)(ws + 12582912);     // [2048,2048]
  __bf16* gatewt = (__bf16*)(ws + 20971520);  // [8192,2048]
  __bf16* linwt = (__bf16*)(ws + 54525952);   // [8192,2048]
  __bf16* outwt = (__bf16*)(ws + 88080384);   // [2048,8192]
  __bf16* xn = (__bf16*)(ws + 121634816);     // [4096,2048]; reused as Ob
  __bf16* QKV = (__bf16*)(ws + 138412032);    // [4096,3072]; reused as an
  __bf16* Vtb = (__bf16*)(ws + 163577856);    // [B,G,128,2048]
  float* abuf = (float*)(ws + 167772160);     // [4096,2048] fp32
  __bf16* hbuf = (__bf16*)(ws + 201326592);   // [4096,8192]
  float* psum = (float*)(ws + 268435456);     // 2x [4096,2048] fp32 split-K partials
  __bf16* Ob = xn;
  __bf16* an = QKV;

  const dim3 tb(32, 8);
  wtrans_kernel<<<dim3(64, 64), tb, 0, stream>>>(wq, wqkvt, 2048, 2048);
  wtrans_kernel<<<dim3(16, 64), tb, 0, stream>>>(wk, wqkvt + (size_t)2048 * 2048, 2048, 512);
  wtrans_kernel<<<dim3(16, 64), tb, 0, stream>>>(wv, wqkvt + (size_t)2560 * 2048, 2048, 512);
  wtrans_kernel<<<dim3(64, 64), tb, 0, stream>>>(wo, wot, 2048, 2048);
  wtrans_kernel<<<dim3(256, 64), tb, 0, stream>>>(gate_w, gatewt, 2048, 8192);
  wtrans_kernel<<<dim3(256, 64), tb, 0, stream>>>(lin_w, linwt, 2048, 8192);
  wtrans_kernel<<<dim3(64, 256), tb, 0, stream>>>(out_w, outwt, 8192, 2048);

  rmsnorm_kernel<<<4096, 256, 0, stream>>>(x, attn_norm_w, xn);

  // fused QKV projection
  gemm256<0><<<dim3(12, 16), 512, 0, stream>>>(xn, wqkvt, QKV, 4096, 3072, 2048, 2048, nullptr, nullptr, nullptr);

  vtrans_kernel<<<dim3(64, 16, 2), tb, 0, stream>>>(QKV + 2560, Vtb, 3072);

  attn_kernel<<<dim3(32, 16), 512, 0, stream>>>(QKV, Vtb, pbias, Ob);

  gemm256<1><<<dim3(8, 16), 512, 0, stream>>>(Ob, wot, abuf, 4096, 2048, 2048, 2048, x, nullptr, nullptr);

  rmsnorm_kernel<<<4096, 256, 0, stream>>>(abuf, linear_norm_w, an);

  // fused FFN: h = silu(an@lin+lb) * (an@gate+gb), one pass over an
  gemmffn<<<dim3(32, 32), 512, 0, stream>>>(an, gatewt, linwt, hbuf, gate_b, lin_b);

  // out-GEMM split-K=2: fp32 partials, fused reduce
  gemm256<5><<<dim3(8, 16, 2), 512, 0, stream>>>(hbuf, outwt, psum, 4096, 2048, 4096, 8192, nullptr, nullptr, nullptr);
  reduce_out_kernel<<<8192, 256, 0, stream>>>(psum, psum + (size_t)4096 * 2048, abuf, out_b, (float*)d_out);
}

// Round 16
// 788.311 us; speedup vs baseline: 1.0550x; 1.0550x over previous
//
#include <hip/hip_runtime.h>
#include <hip/hip_bf16.h>

using bf16x8 = __attribute__((ext_vector_type(8))) __bf16;
using f32x4  = __attribute__((ext_vector_type(4))) float;

constexpr int Bc = 2, Sc = 2048, Dc = 2048, HQc = 16, HKVc = 4, HDc = 128, FFc = 8192;

__device__ __forceinline__ void gload16(const void* g, void* l) {
  __builtin_amdgcn_global_load_lds((const __attribute__((address_space(1))) void*)g,
                                   (__attribute__((address_space(3))) void*)l, 16, 0, 0);
}

// ---------------- transpose-cast: fp32 [R,C] -> bf16 [C,R] ----------------
__global__ __launch_bounds__(256) void wtrans_kernel(const float* __restrict__ in,
                                                     __bf16* __restrict__ out,
                                                     int R, int C) {
  __shared__ float tile[32][33];
  const int tx = threadIdx.x, ty = threadIdx.y;
  const int c0 = blockIdx.x * 32, r0 = blockIdx.y * 32;
#pragma unroll
  for (int i = 0; i < 4; ++i)
    tile[ty + 8 * i][tx] = in[(size_t)(r0 + ty + 8 * i) * C + (c0 + tx)];
  __syncthreads();
#pragma unroll
  for (int i = 0; i < 4; ++i)
    out[(size_t)(c0 + ty + 8 * i) * R + (r0 + tx)] = (__bf16)tile[tx][ty + 8 * i];
}

// ---------------- V slice [.,stride] bf16 -> Vt [B,G,HD,S] bf16 ----------------
__global__ __launch_bounds__(256) void vtrans_kernel(const __bf16* __restrict__ V,
                                                     __bf16* __restrict__ Vt, int stride) {
  __shared__ __bf16 tile[32][33];
  const int tx = threadIdx.x, ty = threadIdx.y;
  const int s0 = blockIdx.x * 32, c0 = blockIdx.y * 32, b = blockIdx.z;
#pragma unroll
  for (int i = 0; i < 4; ++i)
    tile[ty + 8 * i][tx] = V[(size_t)(b * Sc + s0 + ty + 8 * i) * stride + c0 + tx];
  __syncthreads();
#pragma unroll
  for (int i = 0; i < 4; ++i) {
    const int c = c0 + ty + 8 * i;
    Vt[((size_t)(b * HKVc + (c >> 7)) * HDc + (c & 127)) * Sc + s0 + tx] = tile[tx][ty + 8 * i];
  }
}

// ---------------- RMSNorm: fp32 [rows, 2048] -> bf16 ----------------
__global__ __launch_bounds__(256) void rmsnorm_kernel(const float* __restrict__ x,
                                                      const float* __restrict__ w,
                                                      __bf16* __restrict__ out) {
  const int row = blockIdx.x;
  const int t = threadIdx.x;
  const float* xr = x + (size_t)row * Dc + t * 8;
  float4 v0 = *(const float4*)(xr);
  float4 v1 = *(const float4*)(xr + 4);
  float ss = v0.x * v0.x + v0.y * v0.y + v0.z * v0.z + v0.w * v0.w +
             v1.x * v1.x + v1.y * v1.y + v1.z * v1.z + v1.w * v1.w;
#pragma unroll
  for (int off = 32; off > 0; off >>= 1) ss += __shfl_down(ss, off);
  __shared__ float wsum[4];
  if ((t & 63) == 0) wsum[t >> 6] = ss;
  __syncthreads();
  const float tot = wsum[0] + wsum[1] + wsum[2] + wsum[3];
  const float scale = rsqrtf(tot * (1.0f / Dc) + 1e-6f);
  const float* wp = w + t * 8;
  bf16x8 o;
  o[0] = (__bf16)(v0.x * scale * wp[0]);
  o[1] = (__bf16)(v0.y * scale * wp[1]);
  o[2] = (__bf16)(v0.z * scale * wp[2]);
  o[3] = (__bf16)(v0.w * scale * wp[3]);
  o[4] = (__bf16)(v1.x * scale * wp[4]);
  o[5] = (__bf16)(v1.y * scale * wp[5]);
  o[6] = (__bf16)(v1.z * scale * wp[6]);
  o[7] = (__bf16)(v1.w * scale * wp[7]);
  *(bf16x8*)(out + (size_t)row * Dc + t * 8) = o;
}

// ---------------- split-K reduce: out = p0 + p1 + res + bias[col] ----------------
__global__ __launch_bounds__(256) void reduce_out_kernel(const float* __restrict__ p0,
                                                         const float* __restrict__ p1,
                                                         const float* __restrict__ res,
                                                         const float* __restrict__ bias,
                                                         float* __restrict__ out) {
  const size_t i = ((size_t)blockIdx.x * 256 + threadIdx.x) * 4;
  const int col = (int)(i & 2047);
  float4 a = *(const float4*)(p0 + i);
  float4 b = *(const float4*)(p1 + i);
  float4 r = *(const float4*)(res + i);
  float4 bs = *(const float4*)(bias + col);
  float4 o;
  o.x = a.x + b.x + r.x + bs.x;
  o.y = a.y + b.y + r.y + bs.y;
  o.z = a.z + b.z + r.z + bs.z;
  o.w = a.w + b.w + r.w + bs.w;
  *(float4*)(out + i) = o;
}

// ---------------- GEMM 256x256, 4-phase/K-tile, counted vmcnt (r14 state) ----------
// r15 phase-merge REGRESSED (MfmaUtil 41->34): the 4-phase barrier structure creates
// the wave role-split that co-schedules LDS+MFMA pipes. Keep 4-phase.
// Row-major flatten + XCD swizzle. T2 swizzle (conflicts=0).
// EP: 0 bf16; 1 fp32+res; 5 fp32 partial at Cout + z*M*N (split-K)
template <int EP>
__global__ __launch_bounds__(512, 2) void gemm256(
    const __bf16* __restrict__ A, const __bf16* __restrict__ Bt,
    void* __restrict__ Cout, int M, int N, int K, int lda,
    const float* __restrict__ res, const float* __restrict__ bias,
    const __bf16* aux) {
  __shared__ __attribute__((aligned(16))) __bf16 lds[65536];
  const int tid = threadIdx.x;
  const int l = tid & 63, w = tid >> 6;
  const int lm = l & 15, lh = l >> 4;
  const int wr = w >> 2, wc = w & 3;

  int wg = blockIdx.y * gridDim.x + blockIdx.x;
  const int nwg = gridDim.x * gridDim.y;
  wg = (wg & 7) * (nwg >> 3) + (wg >> 3);
  const int bm = (wg / gridDim.x) * 256, bn = (wg % gridDim.x) * 256;
  const int kz = blockIdx.z;

  f32x4 acc[8][4] = {};

  const int srow = w * 16 + (l >> 2);
  const int scol = (((l & 3) ^ ((l >> 3) & 3))) * 8;
  const __bf16* abase = A + (size_t)(bm + srow) * lda + kz * K + scol;
  const __bf16* bbase = Bt + (size_t)(bn + srow) * lda + kz * K + scol;
  const size_t j1 = (size_t)128 * lda;
  const int sdst = w * 512;

  const int xsw = (lm >> 1) & 3;
  const int aoff = (wr * 128 + lm) * 32 + (lh ^ xsw) * 8;
  const int boff = (wc * 64 + lm) * 32 + (lh ^ xsw) * 8;
  const int NT = K >> 6;

  gload16(abase, &lds[sdst]);
  gload16(abase + j1, &lds[4096 + sdst]);
  gload16(bbase, &lds[32768 + sdst]);
  gload16(bbase + j1, &lds[32768 + 4096 + sdst]);
  gload16(abase + 32, &lds[8192 + sdst]);
  gload16(abase + 32 + j1, &lds[8192 + 4096 + sdst]);
  gload16(bbase + 32, &lds[32768 + 8192 + sdst]);
  gload16(bbase + 32 + j1, &lds[32768 + 8192 + 4096 + sdst]);
  gload16(abase + 64, &lds[16384 + sdst]);
  gload16(abase + 64 + j1, &lds[16384 + 4096 + sdst]);
  gload16(bbase + 64, &lds[32768 + 16384 + sdst]);
  gload16(bbase + 64 + j1, &lds[32768 + 16384 + 4096 + sdst]);
  asm volatile("s_waitcnt vmcnt(4)" ::: "memory");
  __builtin_amdgcn_s_barrier();
  __builtin_amdgcn_sched_barrier(0);

  bf16x8 bq[4];
  for (int t = 0; t < NT; ++t) {
    const int pb = (t & 1) * 16384;
    const int qb = 16384 - pb;

    {  // phase 0: ks=0, m 0..3
      bf16x8 af[4];
#pragma unroll
      for (int i = 0; i < 4; ++i) af[i] = *(const bf16x8*)&lds[pb + aoff + i * 512];
#pragma unroll
      for (int n = 0; n < 4; ++n) bq[n] = *(const bf16x8*)&lds[32768 + pb + boff + n * 512];
      if (t + 1 < NT) {
        const __bf16* s = abase + (size_t)(t + 1) * 64 + 32;
        gload16(s, &lds[qb + 8192 + sdst]);
        gload16(s + j1, &lds[qb + 8192 + 4096 + sdst]);
      }
      __builtin_amdgcn_s_barrier();
      __builtin_amdgcn_s_setprio(1);
#pragma unroll
      for (int m = 0; m < 4; ++m)
#pragma unroll
        for (int n = 0; n < 4; ++n)
          acc[m][n] = __builtin_amdgcn_mfma_f32_16x16x32_bf16(af[m], bq[n], acc[m][n], 0, 0, 0);
      __builtin_amdgcn_s_setprio(0);
      __builtin_amdgcn_s_barrier();
    }
    {  // phase 1: ks=0, m 4..7
      bf16x8 af[4];
#pragma unroll
      for (int i = 0; i < 4; ++i) af[i] = *(const bf16x8*)&lds[pb + aoff + 2048 + i * 512];
      if (t + 1 < NT) {
        const __bf16* s = bbase + (size_t)(t + 1) * 64 + 32;
        gload16(s, &lds[32768 + qb + 8192 + sdst]);
        gload16(s + j1, &lds[32768 + qb + 8192 + 4096 + sdst]);
      }
      __builtin_amdgcn_s_barrier();
      __builtin_amdgcn_s_setprio(1);
#pragma unroll
      for (int m = 0; m < 4; ++m)
#pragma unroll
        for (int n = 0; n < 4; ++n)
          acc[m + 4][n] = __builtin_amdgcn_mfma_f32_16x16x32_bf16(af[m], bq[n], acc[m + 4][n], 0, 0, 0);
      __builtin_amdgcn_s_setprio(0);
      __builtin_amdgcn_s_barrier();
    }
    {  // phase 2: ks=1, m 0..3
      bf16x8 af[4];
#pragma unroll
      for (int i = 0; i < 4; ++i) af[i] = *(const bf16x8*)&lds[pb + 8192 + aoff + i * 512];
#pragma unroll
      for (int n = 0; n < 4; ++n) bq[n] = *(const bf16x8*)&lds[32768 + pb + 8192 + boff + n * 512];
      if (t + 2 < NT) {
        const __bf16* s = abase + (size_t)(t + 2) * 64;
        gload16(s, &lds[pb + sdst]);
        gload16(s + j1, &lds[pb + 4096 + sdst]);
      }
      __builtin_amdgcn_s_barrier();
      __builtin_amdgcn_s_setprio(1);
#pragma unroll
      for (int m = 0; m < 4; ++m)
#pragma unroll
        for (int n = 0; n < 4; ++n)
          acc[m][n] = __builtin_amdgcn_mfma_f32_16x16x32_bf16(af[m], bq[n], acc[m][n], 0, 0, 0);
      __builtin_amdgcn_s_setprio(0);
      __builtin_amdgcn_s_barrier();
    }
    {  // phase 3: ks=1, m 4..7 (+ K-tile boundary vmcnt)
      bf16x8 af[4];
#pragma unroll
      for (int i = 0; i < 4; ++i)
        af[i] = *(const bf16x8*)&lds[pb + 8192 + aoff + 2048 + i * 512];
      if (t + 2 < NT) {
        const __bf16* s = bbase + (size_t)(t + 2) * 64;
        gload16(s, &lds[32768 + pb + sdst]);
        gload16(s + j1, &lds[32768 + pb + 4096 + sdst]);
        asm volatile("s_waitcnt vmcnt(4)" ::: "memory");
      } else {
        asm volatile("s_waitcnt vmcnt(0)" ::: "memory");
      }
      __builtin_amdgcn_sched_barrier(0);
      __builtin_amdgcn_s_barrier();
      __builtin_amdgcn_s_setprio(1);
#pragma unroll
      for (int m = 0; m < 4; ++m)
#pragma unroll
        for (int n = 0; n < 4; ++n)
          acc[m + 4][n] = __builtin_amdgcn_mfma_f32_16x16x32_bf16(af[m], bq[n], acc[m + 4][n], 0, 0, 0);
      __builtin_amdgcn_s_setprio(0);
      __builtin_amdgcn_s_barrier();
    }
  }

#pragma unroll
  for (int m = 0; m < 8; ++m) {
#pragma unroll
    for (int n = 0; n < 4; ++n) {
#pragma unroll
      for (int r = 0; r < 4; ++r) {
        const int row = bm + wr * 128 + m * 16 + lh * 4 + r;
        const int col = bn + wc * 64 + n * 16 + lm;
        const size_t idx = (size_t)row * N + col;
        const float v = acc[m][n][r];
        if constexpr (EP == 0) {
          ((__bf16*)Cout)[idx] = (__bf16)v;
        } else if constexpr (EP == 1) {
          ((float*)Cout)[idx] = v + res[idx];
        } else {
          ((float*)Cout)[(size_t)kz * M * N + idx] = v;
        }
      }
    }
  }
}

// ---------------- Fused FFN: H = silu(A@Bl^T + lb) * (A@Bg^T + gb) ----------------
// r14 state (best measured: 304us, MfmaUtil 41%, FETCH 556MB). 4 phases/K-tile,
// 2-col interleave, T2 swizzle, counted vmcnt(4).
__global__ __launch_bounds__(512, 2) void gemmffn(
    const __bf16* __restrict__ A, const __bf16* __restrict__ Bg,
    const __bf16* __restrict__ Bl, __bf16* __restrict__ H,
    const float* __restrict__ gb, const float* __restrict__ lb) {
  __shared__ __attribute__((aligned(16))) __bf16 lds[73728];
  const int tid = threadIdx.x;
  const int l = tid & 63, w = tid >> 6;
  const int lm = l & 15, lh = l >> 4;
  const int wr = w >> 2, wc = w & 3;

  // col-major flatten + XCD swizzle + 2-col interleave within chunk (bijective)
  int wg = blockIdx.x * 32 + blockIdx.y;       // c*32 + m
  wg = (wg & 7) * 128 + (wg >> 3);             // XCD chunk of 128
  const int chunk = wg >> 7;                   // 0..7
  const int within = wg & 127;
  const int cp = within >> 6;                  // col-pair within chunk (0/1)
  const int r2 = within & 63;
  const int bm = (r2 >> 1) * 128;              // m = 0..31
  const int bn = (chunk * 4 + cp * 2 + (r2 & 1)) * 256;

  f32x4 ag[4][4] = {}, al[4][4] = {};

  const int srA = tid >> 2;
  const int scA = ((tid & 3) ^ ((tid >> 3) & 3)) * 8;
  const __bf16* abase = A + (size_t)(bm + srA) * 2048 + scA;
  const int srB = w * 16 + (l >> 2);
  const int scB = (((l & 3) ^ ((l >> 3) & 3))) * 8;
  const __bf16* gbase = Bg + (size_t)(bn + srB) * 2048 + scB;
  const __bf16* lbase = Bl + (size_t)(bn + srB) * 2048 + scB;
  const size_t j1 = (size_t)128 * 2048;
  const int sdst = w * 512;

  const int xsw = (lm >> 1) & 3;
  const int aro = (wr * 64 + lm) * 32 + (lh ^ xsw) * 8;
  const int bro = (wc * 64 + lm) * 32 + (lh ^ xsw) * 8;
  const int NT = 32;  // K=2048 / 64
  // LDS bases: A kh0=0, kh1=4096; Bg = 8192 + d*16384 + kh*8192; Bl = 40960 + ...

  // ---- prologue ----
  gload16(abase, &lds[sdst]);
  gload16(abase + 32, &lds[4096 + sdst]);
  gload16(gbase, &lds[8192 + sdst]);
  gload16(gbase + j1, &lds[8192 + 4096 + sdst]);
  gload16(gbase + 32, &lds[8192 + 8192 + sdst]);
  gload16(gbase + 32 + j1, &lds[8192 + 8192 + 4096 + sdst]);
  gload16(lbase, &lds[40960 + sdst]);
  gload16(lbase + j1, &lds[40960 + 4096 + sdst]);
  gload16(lbase + 32, &lds[40960 + 8192 + sdst]);
  gload16(lbase + 32 + j1, &lds[40960 + 8192 + 4096 + sdst]);
  gload16(gbase + 64, &lds[8192 + 16384 + sdst]);
  gload16(gbase + 64 + j1, &lds[8192 + 16384 + 4096 + sdst]);
  gload16(lbase + 64, &lds[40960 + 16384 + sdst]);
  gload16(lbase + 64 + j1, &lds[40960 + 16384 + 4096 + sdst]);
  asm volatile("s_waitcnt vmcnt(4)" ::: "memory");
  __builtin_amdgcn_s_barrier();
  __builtin_amdgcn_sched_barrier(0);

  for (int t = 0; t < NT; ++t) {
    const int gB = 8192 + (t & 1) * 16384;
    const int lB = 40960 + (t & 1) * 16384;
    const int gBn = 8192 + 16384 - (t & 1) * 16384;
    const int lBn = 40960 + 16384 - (t & 1) * 16384;

    bf16x8 a0[4], a1[4], bq[4];
    {  // phase 0: read A both k-halves + Bg kh0; stage Bg-k1(t+1); MFMA gate ks0
#pragma unroll
      for (int i = 0; i < 4; ++i) a0[i] = *(const bf16x8*)&lds[aro + i * 512];
#pragma unroll
      for (int i = 0; i < 4; ++i) a1[i] = *(const bf16x8*)&lds[4096 + aro + i * 512];
#pragma unroll
      for (int n = 0; n < 4; ++n) bq[n] = *(const bf16x8*)&lds[gB + bro + n * 512];
      if (t + 1 < NT) {
        const __bf16* s = gbase + (size_t)(t + 1) * 64 + 32;
        gload16(s, &lds[gBn + 8192 + sdst]);
        gload16(s + j1, &lds[gBn + 8192 + 4096 + sdst]);
      }
      __builtin_amdgcn_s_barrier();
      __builtin_amdgcn_s_setprio(1);
#pragma unroll
      for (int m = 0; m < 4; ++m)
#pragma unroll
        for (int n = 0; n < 4; ++n)
          ag[m][n] = __builtin_amdgcn_mfma_f32_16x16x32_bf16(a0[m], bq[n], ag[m][n], 0, 0, 0);
      __builtin_amdgcn_s_setprio(0);
      __builtin_amdgcn_s_barrier();
    }
    {  // phase 1: read Bl kh0; stage Bl-k1(t+1); MFMA lin ks0 (a0 reused)
#pragma unroll
      for (int n = 0; n < 4; ++n) bq[n] = *(const bf16x8*)&lds[lB + bro + n * 512];
      if (t + 1 < NT) {
        const __bf16* s = lbase + (size_t)(t + 1) * 64 + 32;
        gload16(s, &lds[lBn + 8192 + sdst]);
        gload16(s + j1, &lds[lBn + 8192 + 4096 + sdst]);
      }
      __builtin_amdgcn_s_barrier();
      __builtin_amdgcn_s_setprio(1);
#pragma unroll
      for (int m = 0; m < 4; ++m)
#pragma unroll
        for (int n = 0; n < 4; ++n)
          al[m][n] = __builtin_amdgcn_mfma_f32_16x16x32_bf16(a0[m], bq[n], al[m][n], 0, 0, 0);
      __builtin_amdgcn_s_setprio(0);
      __builtin_amdgcn_s_barrier();
    }
    {  // phase 2: read Bg kh1; stage A(t+1) both kh + Bg-k0(t+2); MFMA gate ks1
#pragma unroll
      for (int n = 0; n < 4; ++n) bq[n] = *(const bf16x8*)&lds[gB + 8192 + bro + n * 512];
      if (t + 1 < NT) {
        const __bf16* sa = abase + (size_t)(t + 1) * 64;
        gload16(sa, &lds[sdst]);
        gload16(sa + 32, &lds[4096 + sdst]);
      }
      if (t + 2 < NT) {
        const __bf16* s = gbase + (size_t)(t + 2) * 64;
        gload16(s, &lds[gB + sdst]);
        gload16(s + j1, &lds[gB + 4096 + sdst]);
      }
      __builtin_amdgcn_s_barrier();
      __builtin_amdgcn_s_setprio(1);
#pragma unroll
      for (int m = 0; m < 4; ++m)
#pragma unroll
        for (int n = 0; n < 4; ++n)
          ag[m][n] = __builtin_amdgcn_mfma_f32_16x16x32_bf16(a1[m], bq[n], ag[m][n], 0, 0, 0);
      __builtin_amdgcn_s_setprio(0);
      __builtin_amdgcn_s_barrier();
    }
    {  // phase 3: read Bl kh1; stage Bl-k0(t+2); vmcnt; MFMA lin ks1 (a1 reused)
#pragma unroll
      for (int n = 0; n < 4; ++n) bq[n] = *(const bf16x8*)&lds[lB + 8192 + bro + n * 512];
      if (t + 2 < NT) {
        const __bf16* s = lbase + (size_t)(t + 2) * 64;
        gload16(s, &lds[lB + sdst]);
        gload16(s + j1, &lds[lB + 4096 + sdst]);
        asm volatile("s_waitcnt vmcnt(4)" ::: "memory");
      } else {
        asm volatile("s_waitcnt vmcnt(0)" ::: "memory");
      }
      __builtin_amdgcn_sched_barrier(0);
      __builtin_amdgcn_s_barrier();
      __builtin_amdgcn_s_setprio(1);
#pragma unroll
      for (int m = 0; m < 4; ++m)
#pragma unroll
        for (int n = 0; n < 4; ++n)
          al[m][n] = __builtin_amdgcn_mfma_f32_16x16x32_bf16(a1[m], bq[n], al[m][n], 0, 0, 0);
      __builtin_amdgcn_s_setprio(0);
      __builtin_amdgcn_s_barrier();
    }
  }

#pragma unroll
  for (int m = 0; m < 4; ++m) {
#pragma unroll
    for (int n = 0; n < 4; ++n) {
#pragma unroll
      for (int r = 0; r < 4; ++r) {
        const int row = bm + wr * 64 + m * 16 + lh * 4 + r;
        const int col = bn + wc * 64 + n * 16 + lm;
        const float g = ag[m][n][r] + gb[col];
        const float li = al[m][n][r] + lb[col];
        const float sil = li / (1.0f + __expf(-li));
        H[(size_t)row * 8192 + col] = (__bf16)(sil * g);
      }
    }
  }
}

// ---------------- Flash attention, causal + learned additive bias ----------------
// QBLK=128, 512 thr / 8 waves; complementary qtile pairing. r16: T5 setprio around
// MFMA clusters (QK^T + PV) — attn blocks run unsynchronized phases per CU.
__global__ __launch_bounds__(512) void attn_kernel(
    const __bf16* __restrict__ QKV, const __bf16* __restrict__ Vt,
    const float* __restrict__ pbias, __bf16* __restrict__ O) {
  __shared__ __bf16 klds[64][136];
  __shared__ __bf16 vlds[128][72];
  __shared__ __bf16 plds[8][16][72];
  const int tid = threadIdx.x;
  const int w = tid >> 6, l = tid & 63;
  const int lm = l & 15, lh = l >> 4;
  const int by = blockIdx.x;
  const int b = by >> 4, h = by & 15;
  const int g = h >> 2;
  const int qy = blockIdx.y;
  const int qt = (qy < 8) ? qy : (23 - qy);
  const int q0b = qt * 128;
  const int q0 = q0b + w * 16;

  bf16x8 qf[4];
  {
    const __bf16* qbase = QKV + (size_t)(b * Sc + q0 + lm) * 3072 + h * HDc + lh * 8;
#pragma unroll
    for (int ks = 0; ks < 4; ++ks) qf[ks] = *(const bf16x8*)(qbase + ks * 32);
  }

  f32x4 oacc[8] = {};
  float mrow[4] = {-3e38f, -3e38f, -3e38f, -3e38f};
  float lrow[4] = {0.f, 0.f, 0.f, 0.f};
  const float sc_qk = 0.088388347648318447f;

  const __bf16* kgb = QKV + (size_t)b * Sc * 3072 + 2048 + g * 128;
  const __bf16* vgb = Vt + (size_t)(b * HKVc + g) * HDc * Sc;
  const float* pgb = pbias + (size_t)h * Sc * Sc;

  const int skr = tid >> 4;
  const int skc = (tid & 15) * 8;
  const int svr = tid >> 3;
  const int svc = (tid & 7) * 8;

  bf16x8 kreg[2], vreg[2];
  float breg[4][4];

  {
#pragma unroll
    for (int i = 0; i < 2; ++i)
      kreg[i] = *(const bf16x8*)(kgb + (size_t)(i * 32 + skr) * 3072 + skc);
#pragma unroll
    for (int i = 0; i < 2; ++i)
      vreg[i] = *(const bf16x8*)(vgb + (size_t)(i * 64 + svr) * Sc + svc);
#pragma unroll
    for (int c = 0; c < 4; ++c)
#pragma unroll
      for (int r = 0; r < 4; ++r)
        breg[c][r] = pgb[(size_t)(q0 + lh * 4 + r) * Sc + c * 16 + lm];
  }

  const int nt = 2 * qt + 2;
  for (int t = 0; t < nt; ++t) {
    const int kv0 = t * 64;
    __syncthreads();
#pragma unroll
    for (int i = 0; i < 2; ++i) *(bf16x8*)&klds[i * 32 + skr][skc] = kreg[i];
#pragma unroll
    for (int i = 0; i < 2; ++i) *(bf16x8*)&vlds[i * 64 + svr][svc] = vreg[i];
    __syncthreads();

    if (t + 1 < nt) {
      const int nv0 = kv0 + 64;
#pragma unroll
      for (int i = 0; i < 2; ++i)
        kreg[i] = *(const bf16x8*)(kgb + (size_t)(nv0 + i * 32 + skr) * 3072 + skc);
#pragma unroll
      for (int i = 0; i < 2; ++i)
        vreg[i] = *(const bf16x8*)(vgb + (size_t)(i * 64 + svr) * Sc + nv0 + svc);
    }

    float sv[4][4];
    __builtin_amdgcn_s_setprio(1);
#pragma unroll
    for (int c = 0; c < 4; ++c) {
      f32x4 acc = {};
#pragma unroll
      for (int ks = 0; ks < 4; ++ks) {
        bf16x8 kf = *(const bf16x8*)&klds[c * 16 + lm][ks * 32 + lh * 8];
        acc = __builtin_amdgcn_mfma_f32_16x16x32_bf16(qf[ks], kf, acc, 0, 0, 0);
      }
      const int kvg = kv0 + c * 16 + lm;
#pragma unroll
      for (int r = 0; r < 4; ++r) {
        const int qg = q0 + lh * 4 + r;
        sv[c][r] = (kvg <= qg) ? (acc[r] * sc_qk + breg[c][r]) : -1e9f;
      }
    }
    __builtin_amdgcn_s_setprio(0);

    if (t + 1 < nt) {
      const int nv0 = kv0 + 64;
#pragma unroll
      for (int c = 0; c < 4; ++c)
#pragma unroll
        for (int r = 0; r < 4; ++r)
          breg[c][r] = pgb[(size_t)(q0 + lh * 4 + r) * Sc + nv0 + c * 16 + lm];
    }

    float tmv[4];
    bool needb = false;
#pragma unroll
    for (int r = 0; r < 4; ++r) {
      float tm = fmaxf(fmaxf(sv[0][r], sv[1][r]), fmaxf(sv[2][r], sv[3][r]));
      tm = fmaxf(tm, __shfl_xor(tm, 1));
      tm = fmaxf(tm, __shfl_xor(tm, 2));
      tm = fmaxf(tm, __shfl_xor(tm, 4));
      tm = fmaxf(tm, __shfl_xor(tm, 8));
      tmv[r] = tm;
      needb = needb || (tm > mrow[r] + 8.0f);
    }
    if (__any(needb)) {
#pragma unroll
      for (int r = 0; r < 4; ++r) {
        const float mn = fmaxf(mrow[r], tmv[r]);
        const float fac = __expf(mrow[r] - mn);
        mrow[r] = mn;
        lrow[r] *= fac;
#pragma unroll
        for (int d0 = 0; d0 < 8; ++d0) oacc[d0][r] *= fac;
      }
    }
    float pv[4][4];
#pragma unroll
    for (int r = 0; r < 4; ++r) {
      float rs = 0.f;
#pragma unroll
      for (int c = 0; c < 4; ++c) {
        pv[c][r] = __expf(sv[c][r] - mrow[r]);
        rs += pv[c][r];
      }
      rs += __shfl_xor(rs, 1);
      rs += __shfl_xor(rs, 2);
      rs += __shfl_xor(rs, 4);
      rs += __shfl_xor(rs, 8);
      lrow[r] += rs;
    }

#pragma unroll
    for (int c = 0; c < 4; ++c)
#pragma unroll
      for (int r = 0; r < 4; ++r)
        plds[w][lh * 4 + r][c * 16 + lm] = (__bf16)pv[c][r];
    asm volatile("s_waitcnt lgkmcnt(0)" ::: "memory");
    __builtin_amdgcn_sched_barrier(0);
    bf16x8 pa0 = *(const bf16x8*)&plds[w][lm][lh * 8];
    bf16x8 pa1 = *(const bf16x8*)&plds[w][lm][32 + lh * 8];
    __builtin_amdgcn_s_setprio(1);
#pragma unroll
    for (int d0 = 0; d0 < 8; ++d0) {
      bf16x8 vf0 = *(const bf16x8*)&vlds[d0 * 16 + lm][lh * 8];
      bf16x8 vf1 = *(const bf16x8*)&vlds[d0 * 16 + lm][32 + lh * 8];
      oacc[d0] = __builtin_amdgcn_mfma_f32_16x16x32_bf16(pa0, vf0, oacc[d0], 0, 0, 0);
      oacc[d0] = __builtin_amdgcn_mfma_f32_16x16x32_bf16(pa1, vf1, oacc[d0], 0, 0, 0);
    }
    __builtin_amdgcn_s_setprio(0);
  }

  __syncthreads();
  if (w < 4) {
#pragma unroll
    for (int r = 0; r < 4; ++r) {
      const float inv = 1.0f / lrow[r];
#pragma unroll
      for (int d0 = 0; d0 < 8; ++d0)
        klds[w * 16 + lh * 4 + r][d0 * 16 + lm] = (__bf16)(oacc[d0][r] * inv);
    }
    asm volatile("s_waitcnt lgkmcnt(0)" ::: "memory");
    __builtin_amdgcn_sched_barrier(0);
    __bf16* ob = O + ((size_t)(b * Sc + q0 + lm) * HQc + h) * HDc;
#pragma unroll
    for (int c = 0; c < 4; ++c)
      *(bf16x8*)(ob + (c * 4 + lh) * 8) = *(const bf16x8*)&klds[w * 16 + lm][(c * 4 + lh) * 8];
  }
  __syncthreads();
  if (w >= 4) {
    const int wl = w - 4;
#pragma unroll
    for (int r = 0; r < 4; ++r) {
      const float inv = 1.0f / lrow[r];
#pragma unroll
      for (int d0 = 0; d0 < 8; ++d0)
        klds[wl * 16 + lh * 4 + r][d0 * 16 + lm] = (__bf16)(oacc[d0][r] * inv);
    }
    asm volatile("s_waitcnt lgkmcnt(0)" ::: "memory");
    __builtin_amdgcn_sched_barrier(0);
    __bf16* ob = O + ((size_t)(b * Sc + q0 + lm) * HQc + h) * HDc;
#pragma unroll
    for (int c = 0; c < 4; ++c)
      *(bf16x8*)(ob + (c * 4 + lh) * 8) = *(const bf16x8*)&klds[wl * 16 + lm][(c * 4 + lh) * 8];
  }
}

extern "C" void kernel_launch(void* const* d_in, const int* in_sizes, int n_in,
                              void* d_out, int out_size, void* d_ws, size_t ws_size,
                              hipStream_t stream) {
  const float* x = (const float*)d_in[0];
  // d_in[1] = causal mask, applied analytically
  const float* pbias = (const float*)d_in[2];
  const float* wq = (const float*)d_in[3];
  const float* wk = (const float*)d_in[4];
  const float* wv = (const float*)d_in[5];
  const float* wo = (const float*)d_in[6];
  const float* attn_norm_w = (const float*)d_in[7];
  const float* linear_norm_w = (const float*)d_in[8];
  const float* gate_w = (const float*)d_in[9];
  const float* gate_b = (const float*)d_in[10];
  const float* lin_w = (const float*)d_in[11];
  const float* lin_b = (const float*)d_in[12];
  const float* out_w = (const float*)d_in[13];
  const float* out_b = (const float*)d_in[14];

  if (ws_size < 335544320) return;  // layout below needs 320 MB

  char* ws = (char*)d_ws;
  __bf16* wqkvt = (__bf16*)(ws + 0);          // [3072,2048]: wq^T, wk^T, wv^T stacked
  __bf16* wot = (__bf16*)(ws + 12582912);     // [2048,2048]
  __bf16* gatewt = (__bf16*)(ws + 20971520);  // [8192,2048]
  __bf16* linwt = (__bf16*)(ws + 54525952);   // [8192,2048]
  __bf16* outwt = (__bf16*)(ws + 88080384);   // [2048,8192]
  __bf16* xn = (__bf16*)(ws + 121634816);     // [4096,2048]; reused as Ob
  __bf16* QKV = (__bf16*)(ws + 138412032);    // [4096,3072]; reused as an
  __bf16* Vtb = (__bf16*)(ws + 163577856);    // [B,G,128,2048]
  float* abuf = (float*)(ws + 167772160);     // [4096,2048] fp32
  __bf16* hbuf = (__bf16*)(ws + 201326592);   // [4096,8192]
  float* psum = (float*)(ws + 268435456);     // 2x [4096,2048] fp32 split-K partials
  __bf16* Ob = xn;
  __bf16* an = QKV;

  const dim3 tb(32, 8);
  wtrans_kernel<<<dim3(64, 64), tb, 0, stream>>>(wq, wqkvt, 2048, 2048);
  wtrans_kernel<<<dim3(16, 64), tb, 0, stream>>>(wk, wqkvt + (size_t)2048 * 2048, 2048, 512);
  wtrans_kernel<<<dim3(16, 64), tb, 0, stream>>>(wv, wqkvt + (size_t)2560 * 2048, 2048, 512);
  wtrans_kernel<<<dim3(64, 64), tb, 0, stream>>>(wo, wot, 2048, 2048);
  wtrans_kernel<<<dim3(256, 64), tb, 0, stream>>>(gate_w, gatewt, 2048, 8192);
  wtrans_kernel<<<dim3(256, 64), tb, 0, stream>>>(lin_w, linwt, 2048, 8192);
  wtrans_kernel<<<dim3(64, 256), tb, 0, stream>>>(out_w, outwt, 8192, 2048);

  rmsnorm_kernel<<<4096, 256, 0, stream>>>(x, attn_norm_w, xn);

  // fused QKV projection
  gemm256<0><<<dim3(12, 16), 512, 0, stream>>>(xn, wqkvt, QKV, 4096, 3072, 2048, 2048, nullptr, nullptr, nullptr);

  vtrans_kernel<<<dim3(64, 16, 2), tb, 0, stream>>>(QKV + 2560, Vtb, 3072);

  attn_kernel<<<dim3(32, 16), 512, 0, stream>>>(QKV, Vtb, pbias, Ob);

  gemm256<1><<<dim3(8, 16), 512, 0, stream>>>(Ob, wot, abuf, 4096, 2048, 2048, 2048, x, nullptr, nullptr);

  rmsnorm_kernel<<<4096, 256, 0, stream>>>(abuf, linear_norm_w, an);

  // fused FFN: h = silu(an@lin+lb) * (an@gate+gb), one pass over an
  gemmffn<<<dim3(32, 32), 512, 0, stream>>>(an, gatewt, linwt, hbuf, gate_b, lin_b);

  // out-GEMM split-K=2: fp32 partials, fused reduce
  gemm256<5><<<dim3(8, 16, 2), 512, 0, stream>>>(hbuf, outwt, psum, 4096, 2048, 4096, 8192, nullptr, nullptr, nullptr);
  reduce_out_kernel<<<8192, 256, 0, stream>>>(psum, psum + (size_t)4096 * 2048, abuf, out_b, (float*)d_out);
}

// Round 17
// 780.998 us; speedup vs baseline: 1.0649x; 1.0094x over previous
//
#include <hip/hip_runtime.h>
#include <hip/hip_bf16.h>

using bf16x8 = __attribute__((ext_vector_type(8))) __bf16;
using f32x4  = __attribute__((ext_vector_type(4))) float;

constexpr int Bc = 2, Sc = 2048, Dc = 2048, HQc = 16, HKVc = 4, HDc = 128, FFc = 8192;

__device__ __forceinline__ void gload16(const void* g, void* l) {
  __builtin_amdgcn_global_load_lds((const __attribute__((address_space(1))) void*)g,
                                   (__attribute__((address_space(3))) void*)l, 16, 0, 0);
}

// ---------------- transpose-cast: fp32 [R,C] -> bf16 [C,R] ----------------
__global__ __launch_bounds__(256) void wtrans_kernel(const float* __restrict__ in,
                                                     __bf16* __restrict__ out,
                                                     int R, int C) {
  __shared__ float tile[32][33];
  const int tx = threadIdx.x, ty = threadIdx.y;
  const int c0 = blockIdx.x * 32, r0 = blockIdx.y * 32;
#pragma unroll
  for (int i = 0; i < 4; ++i)
    tile[ty + 8 * i][tx] = in[(size_t)(r0 + ty + 8 * i) * C + (c0 + tx)];
  __syncthreads();
#pragma unroll
  for (int i = 0; i < 4; ++i)
    out[(size_t)(c0 + ty + 8 * i) * R + (r0 + tx)] = (__bf16)tile[tx][ty + 8 * i];
}

// ---------------- V slice [.,stride] bf16 -> Vt [B,G,HD,S] bf16 ----------------
__global__ __launch_bounds__(256) void vtrans_kernel(const __bf16* __restrict__ V,
                                                     __bf16* __restrict__ Vt, int stride) {
  __shared__ __bf16 tile[32][33];
  const int tx = threadIdx.x, ty = threadIdx.y;
  const int s0 = blockIdx.x * 32, c0 = blockIdx.y * 32, b = blockIdx.z;
#pragma unroll
  for (int i = 0; i < 4; ++i)
    tile[ty + 8 * i][tx] = V[(size_t)(b * Sc + s0 + ty + 8 * i) * stride + c0 + tx];
  __syncthreads();
#pragma unroll
  for (int i = 0; i < 4; ++i) {
    const int c = c0 + ty + 8 * i;
    Vt[((size_t)(b * HKVc + (c >> 7)) * HDc + (c & 127)) * Sc + s0 + tx] = tile[tx][ty + 8 * i];
  }
}

// ---------------- RMSNorm: fp32 [rows, 2048] -> bf16 ----------------
__global__ __launch_bounds__(256) void rmsnorm_kernel(const float* __restrict__ x,
                                                      const float* __restrict__ w,
                                                      __bf16* __restrict__ out) {
  const int row = blockIdx.x;
  const int t = threadIdx.x;
  const float* xr = x + (size_t)row * Dc + t * 8;
  float4 v0 = *(const float4*)(xr);
  float4 v1 = *(const float4*)(xr + 4);
  float ss = v0.x * v0.x + v0.y * v0.y + v0.z * v0.z + v0.w * v0.w +
             v1.x * v1.x + v1.y * v1.y + v1.z * v1.z + v1.w * v1.w;
#pragma unroll
  for (int off = 32; off > 0; off >>= 1) ss += __shfl_down(ss, off);
  __shared__ float wsum[4];
  if ((t & 63) == 0) wsum[t >> 6] = ss;
  __syncthreads();
  const float tot = wsum[0] + wsum[1] + wsum[2] + wsum[3];
  const float scale = rsqrtf(tot * (1.0f / Dc) + 1e-6f);
  const float* wp = w + t * 8;
  bf16x8 o;
  o[0] = (__bf16)(v0.x * scale * wp[0]);
  o[1] = (__bf16)(v0.y * scale * wp[1]);
  o[2] = (__bf16)(v0.z * scale * wp[2]);
  o[3] = (__bf16)(v0.w * scale * wp[3]);
  o[4] = (__bf16)(v1.x * scale * wp[4]);
  o[5] = (__bf16)(v1.y * scale * wp[5]);
  o[6] = (__bf16)(v1.z * scale * wp[6]);
  o[7] = (__bf16)(v1.w * scale * wp[7]);
  *(bf16x8*)(out + (size_t)row * Dc + t * 8) = o;
}

// ---------------- GEMM BM=128 x BN=256 (gemmffn structure, single B) ----------------
// 512 thr / 8 waves (2x4), wave tile 64x64, acc[4][4]. LDS 96KB:
// A [dbuf 2][kh 2][128x32] (32KB) + B [dbuf 2][kh 2][256x32] (64KB).
// 2 phases/K-tile; A(t+1) staged phase 0 (own dbuf), B-k1(t+1) phase 0,
// B-k0(t+2) phase 1; counted vmcnt(2) at phase 1 (B-k0(t+2) stays in flight).
// Col-major flatten + XCD swizzle (nwg%8==0). T2 swizzle (conflicts=0 verified).
// EP: 0 bf16 out; 1 fp32 out + res; 4 fp32 out res + acc + bias[col]
template <int EP>
__global__ __launch_bounds__(512, 2) void gemm128(
    const __bf16* __restrict__ A, const __bf16* __restrict__ Bt,
    void* __restrict__ Cout, int M, int N, int K, int lda,
    const float* __restrict__ res, const float* __restrict__ bias) {
  __shared__ __attribute__((aligned(16))) __bf16 lds[49152];
  const int tid = threadIdx.x;
  const int l = tid & 63, w = tid >> 6;
  const int lm = l & 15, lh = l >> 4;
  const int wr = w >> 2, wc = w & 3;

  // col-major flatten + XCD swizzle (bijective: nwg % 8 == 0)
  int wg = blockIdx.x * gridDim.y + blockIdx.y;
  const int nwg = gridDim.x * gridDim.y;
  wg = (wg & 7) * (nwg >> 3) + (wg >> 3);
  const int bm = (wg % gridDim.y) * 128;
  const int bn = (wg / gridDim.y) * 256;

  f32x4 acc[4][4] = {};

  // A staging: 1 gload16 per kh (512 thr x 16B = 128x32 elems)
  const int srA = tid >> 2;
  const int scA = ((tid & 3) ^ ((tid >> 3) & 3)) * 8;
  const __bf16* abase = A + (size_t)(bm + srA) * lda + scA;
  // B staging: 2 gload16 per kh (256 rows; 2nd issue lands at +4096 elems)
  const int srB = w * 16 + (l >> 2);
  const int scB = (((l & 3) ^ ((l >> 3) & 3))) * 8;
  const __bf16* bbase = Bt + (size_t)(bn + srB) * lda + scB;
  const size_t j1 = (size_t)128 * lda;
  const int sdst = w * 512;

  const int xsw = (lm >> 1) & 3;
  const int aro = (wr * 64 + lm) * 32 + (lh ^ xsw) * 8;
  const int bro = (wc * 64 + lm) * 32 + (lh ^ xsw) * 8;
  const int NT = K >> 6;
  // LDS elem bases: A = ad*8192 + kh*4096; B = 16384 + bd*16384 + kh*8192

  // ---- prologue: A(0)->buf0, B-k0(0), B-k1(0), B-k0(1) ----
  gload16(abase, &lds[sdst]);
  gload16(abase + 32, &lds[4096 + sdst]);
  gload16(bbase, &lds[16384 + sdst]);
  gload16(bbase + j1, &lds[16384 + 4096 + sdst]);
  gload16(bbase + 32, &lds[16384 + 8192 + sdst]);
  gload16(bbase + 32 + j1, &lds[16384 + 8192 + 4096 + sdst]);
  gload16(bbase + 64, &lds[16384 + 16384 + sdst]);
  gload16(bbase + 64 + j1, &lds[16384 + 16384 + 4096 + sdst]);
  asm volatile("s_waitcnt vmcnt(2)" ::: "memory");  // B-k0(1) stays in flight
  __builtin_amdgcn_s_barrier();
  __builtin_amdgcn_sched_barrier(0);

  for (int t = 0; t < NT; ++t) {
    const int ar = (t & 1) * 8192;         // A read buf
    const int aw = 8192 - ar;              // A write buf (t+1)
    const int pb = 16384 + (t & 1) * 16384;  // B read buf
    const int qb = 16384 + 16384 - (t & 1) * 16384;  // B buf of t+1

    bf16x8 a0[4], a1[4], bq[4];
    {  // phase 0 (kh0): read A both kh + B kh0; stage A(t+1), B-k1(t+1); 16 MFMA
#pragma unroll
      for (int i = 0; i < 4; ++i) a0[i] = *(const bf16x8*)&lds[ar + aro + i * 512];
#pragma unroll
      for (int i = 0; i < 4; ++i) a1[i] = *(const bf16x8*)&lds[ar + 4096 + aro + i * 512];
#pragma unroll
      for (int n = 0; n < 4; ++n) bq[n] = *(const bf16x8*)&lds[pb + bro + n * 512];
      if (t + 1 < NT) {
        const __bf16* sa = abase + (size_t)(t + 1) * 64;
        gload16(sa, &lds[aw + sdst]);
        gload16(sa + 32, &lds[aw + 4096 + sdst]);
        const __bf16* sb = bbase + (size_t)(t + 1) * 64 + 32;
        gload16(sb, &lds[qb + 8192 + sdst]);
        gload16(sb + j1, &lds[qb + 8192 + 4096 + sdst]);
      }
      __builtin_amdgcn_s_barrier();
      __builtin_amdgcn_s_setprio(1);
#pragma unroll
      for (int m = 0; m < 4; ++m)
#pragma unroll
        for (int n = 0; n < 4; ++n)
          acc[m][n] = __builtin_amdgcn_mfma_f32_16x16x32_bf16(a0[m], bq[n], acc[m][n], 0, 0, 0);
      __builtin_amdgcn_s_setprio(0);
      __builtin_amdgcn_s_barrier();
    }
    {  // phase 1 (kh1): read B kh1; stage B-k0(t+2); vmcnt(2); 16 MFMA
#pragma unroll
      for (int n = 0; n < 4; ++n) bq[n] = *(const bf16x8*)&lds[pb + 8192 + bro + n * 512];
      if (t + 2 < NT) {
        const __bf16* sb = bbase + (size_t)(t + 2) * 64;
        gload16(sb, &lds[pb + sdst]);
        gload16(sb + j1, &lds[pb + 4096 + sdst]);
        asm volatile("s_waitcnt vmcnt(2)" ::: "memory");  // drains A(t+1), B-k1(t+1)
      } else {
        asm volatile("s_waitcnt vmcnt(0)" ::: "memory");
      }
      __builtin_amdgcn_sched_barrier(0);
      __builtin_amdgcn_s_barrier();
      __builtin_amdgcn_s_setprio(1);
#pragma unroll
      for (int m = 0; m < 4; ++m)
#pragma unroll
        for (int n = 0; n < 4; ++n)
          acc[m][n] = __builtin_amdgcn_mfma_f32_16x16x32_bf16(a1[m], bq[n], acc[m][n], 0, 0, 0);
      __builtin_amdgcn_s_setprio(0);
      __builtin_amdgcn_s_barrier();
    }
  }

#pragma unroll
  for (int m = 0; m < 4; ++m) {
#pragma unroll
    for (int n = 0; n < 4; ++n) {
#pragma unroll
      for (int r = 0; r < 4; ++r) {
        const int row = bm + wr * 64 + m * 16 + lh * 4 + r;
        const int col = bn + wc * 64 + n * 16 + lm;
        const size_t idx = (size_t)row * N + col;
        const float v = acc[m][n][r];
        if constexpr (EP == 0) {
          ((__bf16*)Cout)[idx] = (__bf16)v;
        } else if constexpr (EP == 1) {
          ((float*)Cout)[idx] = v + res[idx];
        } else {
          ((float*)Cout)[idx] = res[idx] + v + bias[col];
        }
      }
    }
  }
}

// ---------------- Fused FFN: H = silu(A@Bl^T + lb) * (A@Bg^T + gb) ----------------
// r14/r16 state (best measured: ~300us, MfmaUtil 41%, FETCH 556MB). 4 phases/K-tile,
// 2-col interleave, T2 swizzle, counted vmcnt(4).
__global__ __launch_bounds__(512, 2) void gemmffn(
    const __bf16* __restrict__ A, const __bf16* __restrict__ Bg,
    const __bf16* __restrict__ Bl, __bf16* __restrict__ H,
    const float* __restrict__ gb, const float* __restrict__ lb) {
  __shared__ __attribute__((aligned(16))) __bf16 lds[73728];
  const int tid = threadIdx.x;
  const int l = tid & 63, w = tid >> 6;
  const int lm = l & 15, lh = l >> 4;
  const int wr = w >> 2, wc = w & 3;

  // col-major flatten + XCD swizzle + 2-col interleave within chunk (bijective)
  int wg = blockIdx.x * 32 + blockIdx.y;       // c*32 + m
  wg = (wg & 7) * 128 + (wg >> 3);             // XCD chunk of 128
  const int chunk = wg >> 7;                   // 0..7
  const int within = wg & 127;
  const int cp = within >> 6;                  // col-pair within chunk (0/1)
  const int r2 = within & 63;
  const int bm = (r2 >> 1) * 128;              // m = 0..31
  const int bn = (chunk * 4 + cp * 2 + (r2 & 1)) * 256;

  f32x4 ag[4][4] = {}, al[4][4] = {};

  const int srA = tid >> 2;
  const int scA = ((tid & 3) ^ ((tid >> 3) & 3)) * 8;
  const __bf16* abase = A + (size_t)(bm + srA) * 2048 + scA;
  const int srB = w * 16 + (l >> 2);
  const int scB = (((l & 3) ^ ((l >> 3) & 3))) * 8;
  const __bf16* gbase = Bg + (size_t)(bn + srB) * 2048 + scB;
  const __bf16* lbase = Bl + (size_t)(bn + srB) * 2048 + scB;
  const size_t j1 = (size_t)128 * 2048;
  const int sdst = w * 512;

  const int xsw = (lm >> 1) & 3;
  const int aro = (wr * 64 + lm) * 32 + (lh ^ xsw) * 8;
  const int bro = (wc * 64 + lm) * 32 + (lh ^ xsw) * 8;
  const int NT = 32;  // K=2048 / 64
  // LDS bases: A kh0=0, kh1=4096; Bg = 8192 + d*16384 + kh*8192; Bl = 40960 + ...

  // ---- prologue ----
  gload16(abase, &lds[sdst]);
  gload16(abase + 32, &lds[4096 + sdst]);
  gload16(gbase, &lds[8192 + sdst]);
  gload16(gbase + j1, &lds[8192 + 4096 + sdst]);
  gload16(gbase + 32, &lds[8192 + 8192 + sdst]);
  gload16(gbase + 32 + j1, &lds[8192 + 8192 + 4096 + sdst]);
  gload16(lbase, &lds[40960 + sdst]);
  gload16(lbase + j1, &lds[40960 + 4096 + sdst]);
  gload16(lbase + 32, &lds[40960 + 8192 + sdst]);
  gload16(lbase + 32 + j1, &lds[40960 + 8192 + 4096 + sdst]);
  gload16(gbase + 64, &lds[8192 + 16384 + sdst]);
  gload16(gbase + 64 + j1, &lds[8192 + 16384 + 4096 + sdst]);
  gload16(lbase + 64, &lds[40960 + 16384 + sdst]);
  gload16(lbase + 64 + j1, &lds[40960 + 16384 + 4096 + sdst]);
  asm volatile("s_waitcnt vmcnt(4)" ::: "memory");
  __builtin_amdgcn_s_barrier();
  __builtin_amdgcn_sched_barrier(0);

  for (int t = 0; t < NT; ++t) {
    const int gB = 8192 + (t & 1) * 16384;
    const int lB = 40960 + (t & 1) * 16384;
    const int gBn = 8192 + 16384 - (t & 1) * 16384;
    const int lBn = 40960 + 16384 - (t & 1) * 16384;

    bf16x8 a0[4], a1[4], bq[4];
    {  // phase 0: read A both k-halves + Bg kh0; stage Bg-k1(t+1); MFMA gate ks0
#pragma unroll
      for (int i = 0; i < 4; ++i) a0[i] = *(const bf16x8*)&lds[aro + i * 512];
#pragma unroll
      for (int i = 0; i < 4; ++i) a1[i] = *(const bf16x8*)&lds[4096 + aro + i * 512];
#pragma unroll
      for (int n = 0; n < 4; ++n) bq[n] = *(const bf16x8*)&lds[gB + bro + n * 512];
      if (t + 1 < NT) {
        const __bf16* s = gbase + (size_t)(t + 1) * 64 + 32;
        gload16(s, &lds[gBn + 8192 + sdst]);
        gload16(s + j1, &lds[gBn + 8192 + 4096 + sdst]);
      }
      __builtin_amdgcn_s_barrier();
      __builtin_amdgcn_s_setprio(1);
#pragma unroll
      for (int m = 0; m < 4; ++m)
#pragma unroll
        for (int n = 0; n < 4; ++n)
          ag[m][n] = __builtin_amdgcn_mfma_f32_16x16x32_bf16(a0[m], bq[n], ag[m][n], 0, 0, 0);
      __builtin_amdgcn_s_setprio(0);
      __builtin_amdgcn_s_barrier();
    }
    {  // phase 1: read Bl kh0; stage Bl-k1(t+1); MFMA lin ks0 (a0 reused)
#pragma unroll
      for (int n = 0; n < 4; ++n) bq[n] = *(const bf16x8*)&lds[lB + bro + n * 512];
      if (t + 1 < NT) {
        const __bf16* s = lbase + (size_t)(t + 1) * 64 + 32;
        gload16(s, &lds[lBn + 8192 + sdst]);
        gload16(s + j1, &lds[lBn + 8192 + 4096 + sdst]);
      }
      __builtin_amdgcn_s_barrier();
      __builtin_amdgcn_s_setprio(1);
#pragma unroll
      for (int m = 0; m < 4; ++m)
#pragma unroll
        for (int n = 0; n < 4; ++n)
          al[m][n] = __builtin_amdgcn_mfma_f32_16x16x32_bf16(a0[m], bq[n], al[m][n], 0, 0, 0);
      __builtin_amdgcn_s_setprio(0);
      __builtin_amdgcn_s_barrier();
    }
    {  // phase 2: read Bg kh1; stage A(t+1) both kh + Bg-k0(t+2); MFMA gate ks1
#pragma unroll
      for (int n = 0; n < 4; ++n) bq[n] = *(const bf16x8*)&lds[gB + 8192 + bro + n * 512];
      if (t + 1 < NT) {
        const __bf16* sa = abase + (size_t)(t + 1) * 64;
        gload16(sa, &lds[sdst]);
        gload16(sa + 32, &lds[4096 + sdst]);
      }
      if (t + 2 < NT) {
        const __bf16* s = gbase + (size_t)(t + 2) * 64;
        gload16(s, &lds[gB + sdst]);
        gload16(s + j1, &lds[gB + 4096 + sdst]);
      }
      __builtin_amdgcn_s_barrier();
      __builtin_amdgcn_s_setprio(1);
#pragma unroll
      for (int m = 0; m < 4; ++m)
#pragma unroll
        for (int n = 0; n < 4; ++n)
          ag[m][n] = __builtin_amdgcn_mfma_f32_16x16x32_bf16(a1[m], bq[n], ag[m][n], 0, 0, 0);
      __builtin_amdgcn_s_setprio(0);
      __builtin_amdgcn_s_barrier();
    }
    {  // phase 3: read Bl kh1; stage Bl-k0(t+2); vmcnt; MFMA lin ks1 (a1 reused)
#pragma unroll
      for (int n = 0; n < 4; ++n) bq[n] = *(const bf16x8*)&lds[lB + 8192 + bro + n * 512];
      if (t + 2 < NT) {
        const __bf16* s = lbase + (size_t)(t + 2) * 64;
        gload16(s, &lds[lB + sdst]);
        gload16(s + j1, &lds[lB + 4096 + sdst]);
        asm volatile("s_waitcnt vmcnt(4)" ::: "memory");
      } else {
        asm volatile("s_waitcnt vmcnt(0)" ::: "memory");
      }
      __builtin_amdgcn_sched_barrier(0);
      __builtin_amdgcn_s_barrier();
      __builtin_amdgcn_s_setprio(1);
#pragma unroll
      for (int m = 0; m < 4; ++m)
#pragma unroll
        for (int n = 0; n < 4; ++n)
          al[m][n] = __builtin_amdgcn_mfma_f32_16x16x32_bf16(a1[m], bq[n], al[m][n], 0, 0, 0);
      __builtin_amdgcn_s_setprio(0);
      __builtin_amdgcn_s_barrier();
    }
  }

#pragma unroll
  for (int m = 0; m < 4; ++m) {
#pragma unroll
    for (int n = 0; n < 4; ++n) {
#pragma unroll
      for (int r = 0; r < 4; ++r) {
        const int row = bm + wr * 64 + m * 16 + lh * 4 + r;
        const int col = bn + wc * 64 + n * 16 + lm;
        const float g = ag[m][n][r] + gb[col];
        const float li = al[m][n][r] + lb[col];
        const float sil = li / (1.0f + __expf(-li));
        H[(size_t)row * 8192 + col] = (__bf16)(sil * g);
      }
    }
  }
}

// ---------------- Flash attention, causal + learned additive bias ----------------
// QBLK=128, 512 thr / 8 waves; complementary qtile pairing; T5 setprio on MFMA.
__global__ __launch_bounds__(512) void attn_kernel(
    const __bf16* __restrict__ QKV, const __bf16* __restrict__ Vt,
    const float* __restrict__ pbias, __bf16* __restrict__ O) {
  __shared__ __bf16 klds[64][136];
  __shared__ __bf16 vlds[128][72];
  __shared__ __bf16 plds[8][16][72];
  const int tid = threadIdx.x;
  const int w = tid >> 6, l = tid & 63;
  const int lm = l & 15, lh = l >> 4;
  const int by = blockIdx.x;
  const int b = by >> 4, h = by & 15;
  const int g = h >> 2;
  const int qy = blockIdx.y;
  const int qt = (qy < 8) ? qy : (23 - qy);
  const int q0b = qt * 128;
  const int q0 = q0b + w * 16;

  bf16x8 qf[4];
  {
    const __bf16* qbase = QKV + (size_t)(b * Sc + q0 + lm) * 3072 + h * HDc + lh * 8;
#pragma unroll
    for (int ks = 0; ks < 4; ++ks) qf[ks] = *(const bf16x8*)(qbase + ks * 32);
  }

  f32x4 oacc[8] = {};
  float mrow[4] = {-3e38f, -3e38f, -3e38f, -3e38f};
  float lrow[4] = {0.f, 0.f, 0.f, 0.f};
  const float sc_qk = 0.088388347648318447f;

  const __bf16* kgb = QKV + (size_t)b * Sc * 3072 + 2048 + g * 128;
  const __bf16* vgb = Vt + (size_t)(b * HKVc + g) * HDc * Sc;
  const float* pgb = pbias + (size_t)h * Sc * Sc;

  const int skr = tid >> 4;
  const int skc = (tid & 15) * 8;
  const int svr = tid >> 3;
  const int svc = (tid & 7) * 8;

  bf16x8 kreg[2], vreg[2];
  float breg[4][4];

  {
#pragma unroll
    for (int i = 0; i < 2; ++i)
      kreg[i] = *(const bf16x8*)(kgb + (size_t)(i * 32 + skr) * 3072 + skc);
#pragma unroll
    for (int i = 0; i < 2; ++i)
      vreg[i] = *(const bf16x8*)(vgb + (size_t)(i * 64 + svr) * Sc + svc);
#pragma unroll
    for (int c = 0; c < 4; ++c)
#pragma unroll
      for (int r = 0; r < 4; ++r)
        breg[c][r] = pgb[(size_t)(q0 + lh * 4 + r) * Sc + c * 16 + lm];
  }

  const int nt = 2 * qt + 2;
  for (int t = 0; t < nt; ++t) {
    const int kv0 = t * 64;
    __syncthreads();
#pragma unroll
    for (int i = 0; i < 2; ++i) *(bf16x8*)&klds[i * 32 + skr][skc] = kreg[i];
#pragma unroll
    for (int i = 0; i < 2; ++i) *(bf16x8*)&vlds[i * 64 + svr][svc] = vreg[i];
    __syncthreads();

    if (t + 1 < nt) {
      const int nv0 = kv0 + 64;
#pragma unroll
      for (int i = 0; i < 2; ++i)
        kreg[i] = *(const bf16x8*)(kgb + (size_t)(nv0 + i * 32 + skr) * 3072 + skc);
#pragma unroll
      for (int i = 0; i < 2; ++i)
        vreg[i] = *(const bf16x8*)(vgb + (size_t)(i * 64 + svr) * Sc + nv0 + svc);
    }

    float sv[4][4];
    __builtin_amdgcn_s_setprio(1);
#pragma unroll
    for (int c = 0; c < 4; ++c) {
      f32x4 acc = {};
#pragma unroll
      for (int ks = 0; ks < 4; ++ks) {
        bf16x8 kf = *(const bf16x8*)&klds[c * 16 + lm][ks * 32 + lh * 8];
        acc = __builtin_amdgcn_mfma_f32_16x16x32_bf16(qf[ks], kf, acc, 0, 0, 0);
      }
      const int kvg = kv0 + c * 16 + lm;
#pragma unroll
      for (int r = 0; r < 4; ++r) {
        const int qg = q0 + lh * 4 + r;
        sv[c][r] = (kvg <= qg) ? (acc[r] * sc_qk + breg[c][r]) : -1e9f;
      }
    }
    __builtin_amdgcn_s_setprio(0);

    if (t + 1 < nt) {
      const int nv0 = kv0 + 64;
#pragma unroll
      for (int c = 0; c < 4; ++c)
#pragma unroll
        for (int r = 0; r < 4; ++r)
          breg[c][r] = pgb[(size_t)(q0 + lh * 4 + r) * Sc + nv0 + c * 16 + lm];
    }

    float tmv[4];
    bool needb = false;
#pragma unroll
    for (int r = 0; r < 4; ++r) {
      float tm = fmaxf(fmaxf(sv[0][r], sv[1][r]), fmaxf(sv[2][r], sv[3][r]));
      tm = fmaxf(tm, __shfl_xor(tm, 1));
      tm = fmaxf(tm, __shfl_xor(tm, 2));
      tm = fmaxf(tm, __shfl_xor(tm, 4));
      tm = fmaxf(tm, __shfl_xor(tm, 8));
      tmv[r] = tm;
      needb = needb || (tm > mrow[r] + 8.0f);
    }
    if (__any(needb)) {
#pragma unroll
      for (int r = 0; r < 4; ++r) {
        const float mn = fmaxf(mrow[r], tmv[r]);
        const float fac = __expf(mrow[r] - mn);
        mrow[r] = mn;
        lrow[r] *= fac;
#pragma unroll
        for (int d0 = 0; d0 < 8; ++d0) oacc[d0][r] *= fac;
      }
    }
    float pv[4][4];
#pragma unroll
    for (int r = 0; r < 4; ++r) {
      float rs = 0.f;
#pragma unroll
      for (int c = 0; c < 4; ++c) {
        pv[c][r] = __expf(sv[c][r] - mrow[r]);
        rs += pv[c][r];
      }
      rs += __shfl_xor(rs, 1);
      rs += __shfl_xor(rs, 2);
      rs += __shfl_xor(rs, 4);
      rs += __shfl_xor(rs, 8);
      lrow[r] += rs;
    }

#pragma unroll
    for (int c = 0; c < 4; ++c)
#pragma unroll
      for (int r = 0; r < 4; ++r)
        plds[w][lh * 4 + r][c * 16 + lm] = (__bf16)pv[c][r];
    asm volatile("s_waitcnt lgkmcnt(0)" ::: "memory");
    __builtin_amdgcn_sched_barrier(0);
    bf16x8 pa0 = *(const bf16x8*)&plds[w][lm][lh * 8];
    bf16x8 pa1 = *(const bf16x8*)&plds[w][lm][32 + lh * 8];
    __builtin_amdgcn_s_setprio(1);
#pragma unroll
    for (int d0 = 0; d0 < 8; ++d0) {
      bf16x8 vf0 = *(const bf16x8*)&vlds[d0 * 16 + lm][lh * 8];
      bf16x8 vf1 = *(const bf16x8*)&vlds[d0 * 16 + lm][32 + lh * 8];
      oacc[d0] = __builtin_amdgcn_mfma_f32_16x16x32_bf16(pa0, vf0, oacc[d0], 0, 0, 0);
      oacc[d0] = __builtin_amdgcn_mfma_f32_16x16x32_bf16(pa1, vf1, oacc[d0], 0, 0, 0);
    }
    __builtin_amdgcn_s_setprio(0);
  }

  __syncthreads();
  if (w < 4) {
#pragma unroll
    for (int r = 0; r < 4; ++r) {
      const float inv = 1.0f / lrow[r];
#pragma unroll
      for (int d0 = 0; d0 < 8; ++d0)
        klds[w * 16 + lh * 4 + r][d0 * 16 + lm] = (__bf16)(oacc[d0][r] * inv);
    }
    asm volatile("s_waitcnt lgkmcnt(0)" ::: "memory");
    __builtin_amdgcn_sched_barrier(0);
    __bf16* ob = O + ((size_t)(b * Sc + q0 + lm) * HQc + h) * HDc;
#pragma unroll
    for (int c = 0; c < 4; ++c)
      *(bf16x8*)(ob + (c * 4 + lh) * 8) = *(const bf16x8*)&klds[w * 16 + lm][(c * 4 + lh) * 8];
  }
  __syncthreads();
  if (w >= 4) {
    const int wl = w - 4;
#pragma unroll
    for (int r = 0; r < 4; ++r) {
      const float inv = 1.0f / lrow[r];
#pragma unroll
      for (int d0 = 0; d0 < 8; ++d0)
        klds[wl * 16 + lh * 4 + r][d0 * 16 + lm] = (__bf16)(oacc[d0][r] * inv);
    }
    asm volatile("s_waitcnt lgkmcnt(0)" ::: "memory");
    __builtin_amdgcn_sched_barrier(0);
    __bf16* ob = O + ((size_t)(b * Sc + q0 + lm) * HQc + h) * HDc;
#pragma unroll
    for (int c = 0; c < 4; ++c)
      *(bf16x8*)(ob + (c * 4 + lh) * 8) = *(const bf16x8*)&klds[wl * 16 + lm][(c * 4 + lh) * 8];
  }
}

extern "C" void kernel_launch(void* const* d_in, const int* in_sizes, int n_in,
                              void* d_out, int out_size, void* d_ws, size_t ws_size,
                              hipStream_t stream) {
  const float* x = (const float*)d_in[0];
  // d_in[1] = causal mask, applied analytically
  const float* pbias = (const float*)d_in[2];
  const float* wq = (const float*)d_in[3];
  const float* wk = (const float*)d_in[4];
  const float* wv = (const float*)d_in[5];
  const float* wo = (const float*)d_in[6];
  const float* attn_norm_w = (const float*)d_in[7];
  const float* linear_norm_w = (const float*)d_in[8];
  const float* gate_w = (const float*)d_in[9];
  const float* gate_b = (const float*)d_in[10];
  const float* lin_w = (const float*)d_in[11];
  const float* lin_b = (const float*)d_in[12];
  const float* out_w = (const float*)d_in[13];
  const float* out_b = (const float*)d_in[14];

  if (ws_size < 268435456) return;  // layout below needs 256 MB

  char* ws = (char*)d_ws;
  __bf16* wqkvt = (__bf16*)(ws + 0);          // [3072,2048]: wq^T, wk^T, wv^T stacked
  __bf16* wot = (__bf16*)(ws + 12582912);     // [2048,2048]
  __bf16* gatewt = (__bf16*)(ws + 20971520);  // [8192,2048]
  __bf16* linwt = (__bf16*)(ws + 54525952);   // [8192,2048]
  __bf16* outwt = (__bf16*)(ws + 88080384);   // [2048,8192]
  __bf16* xn = (__bf16*)(ws + 121634816);     // [4096,2048]; reused as Ob
  __bf16* QKV = (__bf16*)(ws + 138412032);    // [4096,3072]; reused as an
  __bf16* Vtb = (__bf16*)(ws + 163577856);    // [B,G,128,2048]
  float* abuf = (float*)(ws + 167772160);     // [4096,2048] fp32
  __bf16* hbuf = (__bf16*)(ws + 201326592);   // [4096,8192]
  __bf16* Ob = xn;
  __bf16* an = QKV;

  const dim3 tb(32, 8);
  wtrans_kernel<<<dim3(64, 64), tb, 0, stream>>>(wq, wqkvt, 2048, 2048);
  wtrans_kernel<<<dim3(16, 64), tb, 0, stream>>>(wk, wqkvt + (size_t)2048 * 2048, 2048, 512);
  wtrans_kernel<<<dim3(16, 64), tb, 0, stream>>>(wv, wqkvt + (size_t)2560 * 2048, 2048, 512);
  wtrans_kernel<<<dim3(64, 64), tb, 0, stream>>>(wo, wot, 2048, 2048);
  wtrans_kernel<<<dim3(256, 64), tb, 0, stream>>>(gate_w, gatewt, 2048, 8192);
  wtrans_kernel<<<dim3(256, 64), tb, 0, stream>>>(lin_w, linwt, 2048, 8192);
  wtrans_kernel<<<dim3(64, 256), tb, 0, stream>>>(out_w, outwt, 8192, 2048);

  rmsnorm_kernel<<<4096, 256, 0, stream>>>(x, attn_norm_w, xn);

  // fused QKV projection: 384 blocks (1.5/CU)
  gemm128<0><<<dim3(12, 32), 512, 0, stream>>>(xn, wqkvt, QKV, 4096, 3072, 2048, 2048, nullptr, nullptr);

  vtrans_kernel<<<dim3(64, 16, 2), tb, 0, stream>>>(QKV + 2560, Vtb, 3072);

  attn_kernel<<<dim3(32, 16), 512, 0, stream>>>(QKV, Vtb, pbias, Ob);

  // wo projection + residual: 256 blocks
  gemm128<1><<<dim3(8, 32), 512, 0, stream>>>(Ob, wot, abuf, 4096, 2048, 2048, 2048, x, nullptr);

  rmsnorm_kernel<<<4096, 256, 0, stream>>>(abuf, linear_norm_w, an);

  // fused FFN: h = silu(an@lin+lb) * (an@gate+gb), one pass over an
  gemmffn<<<dim3(32, 32), 512, 0, stream>>>(an, gatewt, linwt, hbuf, gate_b, lin_b);

  // out-GEMM: K=8192, 256 blocks, fused res+bias (no split-K / reduce)
  gemm128<4><<<dim3(8, 32), 512, 0, stream>>>(hbuf, outwt, (float*)d_out, 4096, 2048, 8192, 8192, abuf, out_b);
}

// Round 18
// 766.932 us; speedup vs baseline: 1.0844x; 1.0183x over previous
//
#include <hip/hip_runtime.h>
#include <hip/hip_bf16.h>

using bf16x8 = __attribute__((ext_vector_type(8))) __bf16;
using f32x4  = __attribute__((ext_vector_type(4))) float;

constexpr int Bc = 2, Sc = 2048, Dc = 2048, HQc = 16, HKVc = 4, HDc = 128, FFc = 8192;

__device__ __forceinline__ void gload16(const void* g, void* l) {
  __builtin_amdgcn_global_load_lds((const __attribute__((address_space(1))) void*)g,
                                   (__attribute__((address_space(3))) void*)l, 16, 0, 0);
}

// ------- fused transpose-cast: all 7 weights in ONE launch (kills 6 launch gaps) ----
// job ranges (prefix): wq 4096 | wk 1024 | wv 1024 | wo 4096 | gate 16384 | lin 16384
// | out 16384 = 59392 blocks. Branch is block-uniform. Body identical to verified
// wtrans (fp32 [R,C] tile -> bf16 [C,R]).
__global__ __launch_bounds__(256) void wtrans_all(
    const float* __restrict__ wq, const float* __restrict__ wk,
    const float* __restrict__ wv, const float* __restrict__ wo,
    const float* __restrict__ gw, const float* __restrict__ lw,
    const float* __restrict__ ow, __bf16* __restrict__ wqkvt,
    __bf16* __restrict__ wot, __bf16* __restrict__ gatewt,
    __bf16* __restrict__ linwt, __bf16* __restrict__ outwt) {
  __shared__ float tile[32][33];
  int bid = blockIdx.x;
  const float* in;
  __bf16* out;
  int R, C, tx;
  if (bid < 4096)        { in = wq; out = wqkvt;                        R = 2048; C = 2048; tx = 64; }
  else if (bid < 5120)   { bid -= 4096;  in = wk; out = wqkvt + (size_t)2048 * 2048; R = 2048; C = 512;  tx = 16; }
  else if (bid < 6144)   { bid -= 5120;  in = wv; out = wqkvt + (size_t)2560 * 2048; R = 2048; C = 512;  tx = 16; }
  else if (bid < 10240)  { bid -= 6144;  in = wo; out = wot;            R = 2048; C = 2048; tx = 64; }
  else if (bid < 26624)  { bid -= 10240; in = gw; out = gatewt;         R = 2048; C = 8192; tx = 256; }
  else if (bid < 43008)  { bid -= 26624; in = lw; out = linwt;          R = 2048; C = 8192; tx = 256; }
  else                   { bid -= 43008; in = ow; out = outwt;          R = 8192; C = 2048; tx = 64; }
  const int c0 = (bid % tx) * 32, r0 = (bid / tx) * 32;
  const int txi = threadIdx.x, ty = threadIdx.y;
#pragma unroll
  for (int i = 0; i < 4; ++i)
    tile[ty + 8 * i][txi] = in[(size_t)(r0 + ty + 8 * i) * C + (c0 + txi)];
  __syncthreads();
#pragma unroll
  for (int i = 0; i < 4; ++i)
    out[(size_t)(c0 + ty + 8 * i) * R + (r0 + txi)] = (__bf16)tile[txi][ty + 8 * i];
}

// ---------------- V slice [.,stride] bf16 -> Vt [B,G,HD,S] bf16 ----------------
__global__ __launch_bounds__(256) void vtrans_kernel(const __bf16* __restrict__ V,
                                                     __bf16* __restrict__ Vt, int stride) {
  __shared__ __bf16 tile[32][33];
  const int tx = threadIdx.x, ty = threadIdx.y;
  const int s0 = blockIdx.x * 32, c0 = blockIdx.y * 32, b = blockIdx.z;
#pragma unroll
  for (int i = 0; i < 4; ++i)
    tile[ty + 8 * i][tx] = V[(size_t)(b * Sc + s0 + ty + 8 * i) * stride + c0 + tx];
  __syncthreads();
#pragma unroll
  for (int i = 0; i < 4; ++i) {
    const int c = c0 + ty + 8 * i;
    Vt[((size_t)(b * HKVc + (c >> 7)) * HDc + (c & 127)) * Sc + s0 + tx] = tile[tx][ty + 8 * i];
  }
}

// ---------------- RMSNorm: fp32 [rows, 2048] -> bf16 ----------------
__global__ __launch_bounds__(256) void rmsnorm_kernel(const float* __restrict__ x,
                                                      const float* __restrict__ w,
                                                      __bf16* __restrict__ out) {
  const int row = blockIdx.x;
  const int t = threadIdx.x;
  const float* xr = x + (size_t)row * Dc + t * 8;
  float4 v0 = *(const float4*)(xr);
  float4 v1 = *(const float4*)(xr + 4);
  float ss = v0.x * v0.x + v0.y * v0.y + v0.z * v0.z + v0.w * v0.w +
             v1.x * v1.x + v1.y * v1.y + v1.z * v1.z + v1.w * v1.w;
#pragma unroll
  for (int off = 32; off > 0; off >>= 1) ss += __shfl_down(ss, off);
  __shared__ float wsum[4];
  if ((t & 63) == 0) wsum[t >> 6] = ss;
  __syncthreads();
  const float tot = wsum[0] + wsum[1] + wsum[2] + wsum[3];
  const float scale = rsqrtf(tot * (1.0f / Dc) + 1e-6f);
  const float* wp = w + t * 8;
  bf16x8 o;
  o[0] = (__bf16)(v0.x * scale * wp[0]);
  o[1] = (__bf16)(v0.y * scale * wp[1]);
  o[2] = (__bf16)(v0.z * scale * wp[2]);
  o[3] = (__bf16)(v0.w * scale * wp[3]);
  o[4] = (__bf16)(v1.x * scale * wp[4]);
  o[5] = (__bf16)(v1.y * scale * wp[5]);
  o[6] = (__bf16)(v1.z * scale * wp[6]);
  o[7] = (__bf16)(v1.w * scale * wp[7]);
  *(bf16x8*)(out + (size_t)row * Dc + t * 8) = o;
}

// ---------------- GEMM BM=128 x BN=256 (single B), 2 phases/K-tile ----------------
// 512 thr / 8 waves (2x4), wave tile 64x64, acc[4][4]. LDS 96KB.
// Col-major flatten + XCD swizzle. T2 swizzle (conflicts=0 verified).
// EP: 0 bf16 out; 1 fp32 out + res; 4 fp32 out res + acc + bias[col]
template <int EP>
__global__ __launch_bounds__(512, 2) void gemm128(
    const __bf16* __restrict__ A, const __bf16* __restrict__ Bt,
    void* __restrict__ Cout, int M, int N, int K, int lda,
    const float* __restrict__ res, const float* __restrict__ bias) {
  __shared__ __attribute__((aligned(16))) __bf16 lds[49152];
  const int tid = threadIdx.x;
  const int l = tid & 63, w = tid >> 6;
  const int lm = l & 15, lh = l >> 4;
  const int wr = w >> 2, wc = w & 3;

  int wg = blockIdx.x * gridDim.y + blockIdx.y;
  const int nwg = gridDim.x * gridDim.y;
  wg = (wg & 7) * (nwg >> 3) + (wg >> 3);
  const int bm = (wg % gridDim.y) * 128;
  const int bn = (wg / gridDim.y) * 256;

  f32x4 acc[4][4] = {};

  const int srA = tid >> 2;
  const int scA = ((tid & 3) ^ ((tid >> 3) & 3)) * 8;
  const __bf16* abase = A + (size_t)(bm + srA) * lda + scA;
  const int srB = w * 16 + (l >> 2);
  const int scB = (((l & 3) ^ ((l >> 3) & 3))) * 8;
  const __bf16* bbase = Bt + (size_t)(bn + srB) * lda + scB;
  const size_t j1 = (size_t)128 * lda;
  const int sdst = w * 512;

  const int xsw = (lm >> 1) & 3;
  const int aro = (wr * 64 + lm) * 32 + (lh ^ xsw) * 8;
  const int bro = (wc * 64 + lm) * 32 + (lh ^ xsw) * 8;
  const int NT = K >> 6;

  gload16(abase, &lds[sdst]);
  gload16(abase + 32, &lds[4096 + sdst]);
  gload16(bbase, &lds[16384 + sdst]);
  gload16(bbase + j1, &lds[16384 + 4096 + sdst]);
  gload16(bbase + 32, &lds[16384 + 8192 + sdst]);
  gload16(bbase + 32 + j1, &lds[16384 + 8192 + 4096 + sdst]);
  gload16(bbase + 64, &lds[16384 + 16384 + sdst]);
  gload16(bbase + 64 + j1, &lds[16384 + 16384 + 4096 + sdst]);
  asm volatile("s_waitcnt vmcnt(2)" ::: "memory");
  __builtin_amdgcn_s_barrier();
  __builtin_amdgcn_sched_barrier(0);

  for (int t = 0; t < NT; ++t) {
    const int ar = (t & 1) * 8192;
    const int aw = 8192 - ar;
    const int pb = 16384 + (t & 1) * 16384;
    const int qb = 16384 + 16384 - (t & 1) * 16384;

    bf16x8 a0[4], a1[4], bq[4];
    {  // phase 0 (kh0)
#pragma unroll
      for (int i = 0; i < 4; ++i) a0[i] = *(const bf16x8*)&lds[ar + aro + i * 512];
#pragma unroll
      for (int i = 0; i < 4; ++i) a1[i] = *(const bf16x8*)&lds[ar + 4096 + aro + i * 512];
#pragma unroll
      for (int n = 0; n < 4; ++n) bq[n] = *(const bf16x8*)&lds[pb + bro + n * 512];
      if (t + 1 < NT) {
        const __bf16* sa = abase + (size_t)(t + 1) * 64;
        gload16(sa, &lds[aw + sdst]);
        gload16(sa + 32, &lds[aw + 4096 + sdst]);
        const __bf16* sb = bbase + (size_t)(t + 1) * 64 + 32;
        gload16(sb, &lds[qb + 8192 + sdst]);
        gload16(sb + j1, &lds[qb + 8192 + 4096 + sdst]);
      }
      __builtin_amdgcn_s_barrier();
      __builtin_amdgcn_s_setprio(1);
#pragma unroll
      for (int m = 0; m < 4; ++m)
#pragma unroll
        for (int n = 0; n < 4; ++n)
          acc[m][n] = __builtin_amdgcn_mfma_f32_16x16x32_bf16(a0[m], bq[n], acc[m][n], 0, 0, 0);
      __builtin_amdgcn_s_setprio(0);
      __builtin_amdgcn_s_barrier();
    }
    {  // phase 1 (kh1)
#pragma unroll
      for (int n = 0; n < 4; ++n) bq[n] = *(const bf16x8*)&lds[pb + 8192 + bro + n * 512];
      if (t + 2 < NT) {
        const __bf16* sb = bbase + (size_t)(t + 2) * 64;
        gload16(sb, &lds[pb + sdst]);
        gload16(sb + j1, &lds[pb + 4096 + sdst]);
        asm volatile("s_waitcnt vmcnt(2)" ::: "memory");
      } else {
        asm volatile("s_waitcnt vmcnt(0)" ::: "memory");
      }
      __builtin_amdgcn_sched_barrier(0);
      __builtin_amdgcn_s_barrier();
      __builtin_amdgcn_s_setprio(1);
#pragma unroll
      for (int m = 0; m < 4; ++m)
#pragma unroll
        for (int n = 0; n < 4; ++n)
          acc[m][n] = __builtin_amdgcn_mfma_f32_16x16x32_bf16(a1[m], bq[n], acc[m][n], 0, 0, 0);
      __builtin_amdgcn_s_setprio(0);
      __builtin_amdgcn_s_barrier();
    }
  }

#pragma unroll
  for (int m = 0; m < 4; ++m) {
#pragma unroll
    for (int n = 0; n < 4; ++n) {
#pragma unroll
      for (int r = 0; r < 4; ++r) {
        const int row = bm + wr * 64 + m * 16 + lh * 4 + r;
        const int col = bn + wc * 64 + n * 16 + lm;
        const size_t idx = (size_t)row * N + col;
        const float v = acc[m][n][r];
        if constexpr (EP == 0) {
          ((__bf16*)Cout)[idx] = (__bf16)v;
        } else if constexpr (EP == 1) {
          ((float*)Cout)[idx] = v + res[idx];
        } else {
          ((float*)Cout)[idx] = res[idx] + v + bias[col];
        }
      }
    }
  }
}

// ---------------- Fused FFN: H = silu(A@Bl^T + lb) * (A@Bg^T + gb) ----------------
// Stable best: ~301us, 913 TF, MfmaUtil 41%, FETCH 556MB, conflicts 0.
__global__ __launch_bounds__(512, 2) void gemmffn(
    const __bf16* __restrict__ A, const __bf16* __restrict__ Bg,
    const __bf16* __restrict__ Bl, __bf16* __restrict__ H,
    const float* __restrict__ gb, const float* __restrict__ lb) {
  __shared__ __attribute__((aligned(16))) __bf16 lds[73728];
  const int tid = threadIdx.x;
  const int l = tid & 63, w = tid >> 6;
  const int lm = l & 15, lh = l >> 4;
  const int wr = w >> 2, wc = w & 3;

  int wg = blockIdx.x * 32 + blockIdx.y;
  wg = (wg & 7) * 128 + (wg >> 3);
  const int chunk = wg >> 7;
  const int within = wg & 127;
  const int cp = within >> 6;
  const int r2 = within & 63;
  const int bm = (r2 >> 1) * 128;
  const int bn = (chunk * 4 + cp * 2 + (r2 & 1)) * 256;

  f32x4 ag[4][4] = {}, al[4][4] = {};

  const int srA = tid >> 2;
  const int scA = ((tid & 3) ^ ((tid >> 3) & 3)) * 8;
  const __bf16* abase = A + (size_t)(bm + srA) * 2048 + scA;
  const int srB = w * 16 + (l >> 2);
  const int scB = (((l & 3) ^ ((l >> 3) & 3))) * 8;
  const __bf16* gbase = Bg + (size_t)(bn + srB) * 2048 + scB;
  const __bf16* lbase = Bl + (size_t)(bn + srB) * 2048 + scB;
  const size_t j1 = (size_t)128 * 2048;
  const int sdst = w * 512;

  const int xsw = (lm >> 1) & 3;
  const int aro = (wr * 64 + lm) * 32 + (lh ^ xsw) * 8;
  const int bro = (wc * 64 + lm) * 32 + (lh ^ xsw) * 8;
  const int NT = 32;

  gload16(abase, &lds[sdst]);
  gload16(abase + 32, &lds[4096 + sdst]);
  gload16(gbase, &lds[8192 + sdst]);
  gload16(gbase + j1, &lds[8192 + 4096 + sdst]);
  gload16(gbase + 32, &lds[8192 + 8192 + sdst]);
  gload16(gbase + 32 + j1, &lds[8192 + 8192 + 4096 + sdst]);
  gload16(lbase, &lds[40960 + sdst]);
  gload16(lbase + j1, &lds[40960 + 4096 + sdst]);
  gload16(lbase + 32, &lds[40960 + 8192 + sdst]);
  gload16(lbase + 32 + j1, &lds[40960 + 8192 + 4096 + sdst]);
  gload16(gbase + 64, &lds[8192 + 16384 + sdst]);
  gload16(gbase + 64 + j1, &lds[8192 + 16384 + 4096 + sdst]);
  gload16(lbase + 64, &lds[40960 + 16384 + sdst]);
  gload16(lbase + 64 + j1, &lds[40960 + 16384 + 4096 + sdst]);
  asm volatile("s_waitcnt vmcnt(4)" ::: "memory");
  __builtin_amdgcn_s_barrier();
  __builtin_amdgcn_sched_barrier(0);

  for (int t = 0; t < NT; ++t) {
    const int gB = 8192 + (t & 1) * 16384;
    const int lB = 40960 + (t & 1) * 16384;
    const int gBn = 8192 + 16384 - (t & 1) * 16384;
    const int lBn = 40960 + 16384 - (t & 1) * 16384;

    bf16x8 a0[4], a1[4], bq[4];
    {  // phase 0
#pragma unroll
      for (int i = 0; i < 4; ++i) a0[i] = *(const bf16x8*)&lds[aro + i * 512];
#pragma unroll
      for (int i = 0; i < 4; ++i) a1[i] = *(const bf16x8*)&lds[4096 + aro + i * 512];
#pragma unroll
      for (int n = 0; n < 4; ++n) bq[n] = *(const bf16x8*)&lds[gB + bro + n * 512];
      if (t + 1 < NT) {
        const __bf16* s = gbase + (size_t)(t + 1) * 64 + 32;
        gload16(s, &lds[gBn + 8192 + sdst]);
        gload16(s + j1, &lds[gBn + 8192 + 4096 + sdst]);
      }
      __builtin_amdgcn_s_barrier();
      __builtin_amdgcn_s_setprio(1);
#pragma unroll
      for (int m = 0; m < 4; ++m)
#pragma unroll
        for (int n = 0; n < 4; ++n)
          ag[m][n] = __builtin_amdgcn_mfma_f32_16x16x32_bf16(a0[m], bq[n], ag[m][n], 0, 0, 0);
      __builtin_amdgcn_s_setprio(0);
      __builtin_amdgcn_s_barrier();
    }
    {  // phase 1
#pragma unroll
      for (int n = 0; n < 4; ++n) bq[n] = *(const bf16x8*)&lds[lB + bro + n * 512];
      if (t + 1 < NT) {
        const __bf16* s = lbase + (size_t)(t + 1) * 64 + 32;
        gload16(s, &lds[lBn + 8192 + sdst]);
        gload16(s + j1, &lds[lBn + 8192 + 4096 + sdst]);
      }
      __builtin_amdgcn_s_barrier();
      __builtin_amdgcn_s_setprio(1);
#pragma unroll
      for (int m = 0; m < 4; ++m)
#pragma unroll
        for (int n = 0; n < 4; ++n)
          al[m][n] = __builtin_amdgcn_mfma_f32_16x16x32_bf16(a0[m], bq[n], al[m][n], 0, 0, 0);
      __builtin_amdgcn_s_setprio(0);
      __builtin_amdgcn_s_barrier();
    }
    {  // phase 2
#pragma unroll
      for (int n = 0; n < 4; ++n) bq[n] = *(const bf16x8*)&lds[gB + 8192 + bro + n * 512];
      if (t + 1 < NT) {
        const __bf16* sa = abase + (size_t)(t + 1) * 64;
        gload16(sa, &lds[sdst]);
        gload16(sa + 32, &lds[4096 + sdst]);
      }
      if (t + 2 < NT) {
        const __bf16* s = gbase + (size_t)(t + 2) * 64;
        gload16(s, &lds[gB + sdst]);
        gload16(s + j1, &lds[gB + 4096 + sdst]);
      }
      __builtin_amdgcn_s_barrier();
      __builtin_amdgcn_s_setprio(1);
#pragma unroll
      for (int m = 0; m < 4; ++m)
#pragma unroll
        for (int n = 0; n < 4; ++n)
          ag[m][n] = __builtin_amdgcn_mfma_f32_16x16x32_bf16(a1[m], bq[n], ag[m][n], 0, 0, 0);
      __builtin_amdgcn_s_setprio(0);
      __builtin_amdgcn_s_barrier();
    }
    {  // phase 3
#pragma unroll
      for (int n = 0; n < 4; ++n) bq[n] = *(const bf16x8*)&lds[lB + 8192 + bro + n * 512];
      if (t + 2 < NT) {
        const __bf16* s = lbase + (size_t)(t + 2) * 64;
        gload16(s, &lds[lB + sdst]);
        gload16(s + j1, &lds[lB + 4096 + sdst]);
        asm volatile("s_waitcnt vmcnt(4)" ::: "memory");
      } else {
        asm volatile("s_waitcnt vmcnt(0)" ::: "memory");
      }
      __builtin_amdgcn_sched_barrier(0);
      __builtin_amdgcn_s_barrier();
      __builtin_amdgcn_s_setprio(1);
#pragma unroll
      for (int m = 0; m < 4; ++m)
#pragma unroll
        for (int n = 0; n < 4; ++n)
          al[m][n] = __builtin_amdgcn_mfma_f32_16x16x32_bf16(a1[m], bq[n], al[m][n], 0, 0, 0);
      __builtin_amdgcn_s_setprio(0);
      __builtin_amdgcn_s_barrier();
    }
  }

#pragma unroll
  for (int m = 0; m < 4; ++m) {
#pragma unroll
    for (int n = 0; n < 4; ++n) {
#pragma unroll
      for (int r = 0; r < 4; ++r) {
        const int row = bm + wr * 64 + m * 16 + lh * 4 + r;
        const int col = bn + wc * 64 + n * 16 + lm;
        const float g = ag[m][n][r] + gb[col];
        const float li = al[m][n][r] + lb[col];
        const float sil = li / (1.0f + __expf(-li));
        H[(size_t)row * 8192 + col] = (__bf16)(sil * g);
      }
    }
  }
}

// ---------------- Flash attention, causal + learned additive bias ----------------
__global__ __launch_bounds__(512) void attn_kernel(
    const __bf16* __restrict__ QKV, const __bf16* __restrict__ Vt,
    const float* __restrict__ pbias, __bf16* __restrict__ O) {
  __shared__ __bf16 klds[64][136];
  __shared__ __bf16 vlds[128][72];
  __shared__ __bf16 plds[8][16][72];
  const int tid = threadIdx.x;
  const int w = tid >> 6, l = tid & 63;
  const int lm = l & 15, lh = l >> 4;
  const int by = blockIdx.x;
  const int b = by >> 4, h = by & 15;
  const int g = h >> 2;
  const int qy = blockIdx.y;
  const int qt = (qy < 8) ? qy : (23 - qy);
  const int q0b = qt * 128;
  const int q0 = q0b + w * 16;

  bf16x8 qf[4];
  {
    const __bf16* qbase = QKV + (size_t)(b * Sc + q0 + lm) * 3072 + h * HDc + lh * 8;
#pragma unroll
    for (int ks = 0; ks < 4; ++ks) qf[ks] = *(const bf16x8*)(qbase + ks * 32);
  }

  f32x4 oacc[8] = {};
  float mrow[4] = {-3e38f, -3e38f, -3e38f, -3e38f};
  float lrow[4] = {0.f, 0.f, 0.f, 0.f};
  const float sc_qk = 0.088388347648318447f;

  const __bf16* kgb = QKV + (size_t)b * Sc * 3072 + 2048 + g * 128;
  const __bf16* vgb = Vt + (size_t)(b * HKVc + g) * HDc * Sc;
  const float* pgb = pbias + (size_t)h * Sc * Sc;

  const int skr = tid >> 4;
  const int skc = (tid & 15) * 8;
  const int svr = tid >> 3;
  const int svc = (tid & 7) * 8;

  bf16x8 kreg[2], vreg[2];
  float breg[4][4];

  {
#pragma unroll
    for (int i = 0; i < 2; ++i)
      kreg[i] = *(const bf16x8*)(kgb + (size_t)(i * 32 + skr) * 3072 + skc);
#pragma unroll
    for (int i = 0; i < 2; ++i)
      vreg[i] = *(const bf16x8*)(vgb + (size_t)(i * 64 + svr) * Sc + svc);
#pragma unroll
    for (int c = 0; c < 4; ++c)
#pragma unroll
      for (int r = 0; r < 4; ++r)
        breg[c][r] = pgb[(size_t)(q0 + lh * 4 + r) * Sc + c * 16 + lm];
  }

  const int nt = 2 * qt + 2;
  for (int t = 0; t < nt; ++t) {
    const int kv0 = t * 64;
    __syncthreads();
#pragma unroll
    for (int i = 0; i < 2; ++i) *(bf16x8*)&klds[i * 32 + skr][skc] = kreg[i];
#pragma unroll
    for (int i = 0; i < 2; ++i) *(bf16x8*)&vlds[i * 64 + svr][svc] = vreg[i];
    __syncthreads();

    if (t + 1 < nt) {
      const int nv0 = kv0 + 64;
#pragma unroll
      for (int i = 0; i < 2; ++i)
        kreg[i] = *(const bf16x8*)(kgb + (size_t)(nv0 + i * 32 + skr) * 3072 + skc);
#pragma unroll
      for (int i = 0; i < 2; ++i)
        vreg[i] = *(const bf16x8*)(vgb + (size_t)(i * 64 + svr) * Sc + nv0 + svc);
    }

    float sv[4][4];
    __builtin_amdgcn_s_setprio(1);
#pragma unroll
    for (int c = 0; c < 4; ++c) {
      f32x4 acc = {};
#pragma unroll
      for (int ks = 0; ks < 4; ++ks) {
        bf16x8 kf = *(const bf16x8*)&klds[c * 16 + lm][ks * 32 + lh * 8];
        acc = __builtin_amdgcn_mfma_f32_16x16x32_bf16(qf[ks], kf, acc, 0, 0, 0);
      }
      const int kvg = kv0 + c * 16 + lm;
#pragma unroll
      for (int r = 0; r < 4; ++r) {
        const int qg = q0 + lh * 4 + r;
        sv[c][r] = (kvg <= qg) ? (acc[r] * sc_qk + breg[c][r]) : -1e9f;
      }
    }
    __builtin_amdgcn_s_setprio(0);

    if (t + 1 < nt) {
      const int nv0 = kv0 + 64;
#pragma unroll
      for (int c = 0; c < 4; ++c)
#pragma unroll
        for (int r = 0; r < 4; ++r)
          breg[c][r] = pgb[(size_t)(q0 + lh * 4 + r) * Sc + nv0 + c * 16 + lm];
    }

    float tmv[4];
    bool needb = false;
#pragma unroll
    for (int r = 0; r < 4; ++r) {
      float tm = fmaxf(fmaxf(sv[0][r], sv[1][r]), fmaxf(sv[2][r], sv[3][r]));
      tm = fmaxf(tm, __shfl_xor(tm, 1));
      tm = fmaxf(tm, __shfl_xor(tm, 2));
      tm = fmaxf(tm, __shfl_xor(tm, 4));
      tm = fmaxf(tm, __shfl_xor(tm, 8));
      tmv[r] = tm;
      needb = needb || (tm > mrow[r] + 8.0f);
    }
    if (__any(needb)) {
#pragma unroll
      for (int r = 0; r < 4; ++r) {
        const float mn = fmaxf(mrow[r], tmv[r]);
        const float fac = __expf(mrow[r] - mn);
        mrow[r] = mn;
        lrow[r] *= fac;
#pragma unroll
        for (int d0 = 0; d0 < 8; ++d0) oacc[d0][r] *= fac;
      }
    }
    float pv[4][4];
#pragma unroll
    for (int r = 0; r < 4; ++r) {
      float rs = 0.f;
#pragma unroll
      for (int c = 0; c < 4; ++c) {
        pv[c][r] = __expf(sv[c][r] - mrow[r]);
        rs += pv[c][r];
      }
      rs += __shfl_xor(rs, 1);
      rs += __shfl_xor(rs, 2);
      rs += __shfl_xor(rs, 4);
      rs += __shfl_xor(rs, 8);
      lrow[r] += rs;
    }

#pragma unroll
    for (int c = 0; c < 4; ++c)
#pragma unroll
      for (int r = 0; r < 4; ++r)
        plds[w][lh * 4 + r][c * 16 + lm] = (__bf16)pv[c][r];
    asm volatile("s_waitcnt lgkmcnt(0)" ::: "memory");
    __builtin_amdgcn_sched_barrier(0);
    bf16x8 pa0 = *(const bf16x8*)&plds[w][lm][lh * 8];
    bf16x8 pa1 = *(const bf16x8*)&plds[w][lm][32 + lh * 8];
    __builtin_amdgcn_s_setprio(1);
#pragma unroll
    for (int d0 = 0; d0 < 8; ++d0) {
      bf16x8 vf0 = *(const bf16x8*)&vlds[d0 * 16 + lm][lh * 8];
      bf16x8 vf1 = *(const bf16x8*)&vlds[d0 * 16 + lm][32 + lh * 8];
      oacc[d0] = __builtin_amdgcn_mfma_f32_16x16x32_bf16(pa0, vf0, oacc[d0], 0, 0, 0);
      oacc[d0] = __builtin_amdgcn_mfma_f32_16x16x32_bf16(pa1, vf1, oacc[d0], 0, 0, 0);
    }
    __builtin_amdgcn_s_setprio(0);
  }

  __syncthreads();
  if (w < 4) {
#pragma unroll
    for (int r = 0; r < 4; ++r) {
      const float inv = 1.0f / lrow[r];
#pragma unroll
      for (int d0 = 0; d0 < 8; ++d0)
        klds[w * 16 + lh * 4 + r][d0 * 16 + lm] = (__bf16)(oacc[d0][r] * inv);
    }
    asm volatile("s_waitcnt lgkmcnt(0)" ::: "memory");
    __builtin_amdgcn_sched_barrier(0);
    __bf16* ob = O + ((size_t)(b * Sc + q0 + lm) * HQc + h) * HDc;
#pragma unroll
    for (int c = 0; c < 4; ++c)
      *(bf16x8*)(ob + (c * 4 + lh) * 8) = *(const bf16x8*)&klds[w * 16 + lm][(c * 4 + lh) * 8];
  }
  __syncthreads();
  if (w >= 4) {
    const int wl = w - 4;
#pragma unroll
    for (int r = 0; r < 4; ++r) {
      const float inv = 1.0f / lrow[r];
#pragma unroll
      for (int d0 = 0; d0 < 8; ++d0)
        klds[wl * 16 + lh * 4 + r][d0 * 16 + lm] = (__bf16)(oacc[d0][r] * inv);
    }
    asm volatile("s_waitcnt lgkmcnt(0)" ::: "memory");
    __builtin_amdgcn_sched_barrier(0);
    __bf16* ob = O + ((size_t)(b * Sc + q0 + lm) * HQc + h) * HDc;
#pragma unroll
    for (int c = 0; c < 4; ++c)
      *(bf16x8*)(ob + (c * 4 + lh) * 8) = *(const bf16x8*)&klds[wl * 16 + lm][(c * 4 + lh) * 8];
  }
}

extern "C" void kernel_launch(void* const* d_in, const int* in_sizes, int n_in,
                              void* d_out, int out_size, void* d_ws, size_t ws_size,
                              hipStream_t stream) {
  const float* x = (const float*)d_in[0];
  // d_in[1] = causal mask, applied analytically
  const float* pbias = (const float*)d_in[2];
  const float* wq = (const float*)d_in[3];
  const float* wk = (const float*)d_in[4];
  const float* wv = (const float*)d_in[5];
  const float* wo = (const float*)d_in[6];
  const float* attn_norm_w = (const float*)d_in[7];
  const float* linear_norm_w = (const float*)d_in[8];
  const float* gate_w = (const float*)d_in[9];
  const float* gate_b = (const float*)d_in[10];
  const float* lin_w = (const float*)d_in[11];
  const float* lin_b = (const float*)d_in[12];
  const float* out_w = (const float*)d_in[13];
  const float* out_b = (const float*)d_in[14];

  if (ws_size < 268435456) return;  // layout below needs 256 MB

  char* ws = (char*)d_ws;
  __bf16* wqkvt = (__bf16*)(ws + 0);          // [3072,2048]: wq^T, wk^T, wv^T stacked
  __bf16* wot = (__bf16*)(ws + 12582912);     // [2048,2048]
  __bf16* gatewt = (__bf16*)(ws + 20971520);  // [8192,2048]
  __bf16* linwt = (__bf16*)(ws + 54525952);   // [8192,2048]
  __bf16* outwt = (__bf16*)(ws + 88080384);   // [2048,8192]
  __bf16* xn = (__bf16*)(ws + 121634816);     // [4096,2048]; reused as Ob
  __bf16* QKV = (__bf16*)(ws + 138412032);    // [4096,3072]; reused as an
  __bf16* Vtb = (__bf16*)(ws + 163577856);    // [B,G,128,2048]
  float* abuf = (float*)(ws + 167772160);     // [4096,2048] fp32
  __bf16* hbuf = (__bf16*)(ws + 201326592);   // [4096,8192]
  __bf16* Ob = xn;
  __bf16* an = QKV;

  // all 7 weight transposes in ONE launch (kills 6 launch gaps)
  wtrans_all<<<59392, dim3(32, 8), 0, stream>>>(wq, wk, wv, wo, gate_w, lin_w, out_w,
                                                wqkvt, wot, gatewt, linwt, outwt);

  rmsnorm_kernel<<<4096, 256, 0, stream>>>(x, attn_norm_w, xn);

  // fused QKV projection: 384 blocks
  gemm128<0><<<dim3(12, 32), 512, 0, stream>>>(xn, wqkvt, QKV, 4096, 3072, 2048, 2048, nullptr, nullptr);

  vtrans_kernel<<<dim3(64, 16, 2), dim3(32, 8), 0, stream>>>(QKV + 2560, Vtb, 3072);

  attn_kernel<<<dim3(32, 16), 512, 0, stream>>>(QKV, Vtb, pbias, Ob);

  // wo projection + residual: 256 blocks
  gemm128<1><<<dim3(8, 32), 512, 0, stream>>>(Ob, wot, abuf, 4096, 2048, 2048, 2048, x, nullptr);

  rmsnorm_kernel<<<4096, 256, 0, stream>>>(abuf, linear_norm_w, an);

  // fused FFN: h = silu(an@lin+lb) * (an@gate+gb), one pass over an
  gemmffn<<<dim3(32, 32), 512, 0, stream>>>(an, gatewt, linwt, hbuf, gate_b, lin_b);

  // out-GEMM: K=8192, 256 blocks, fused res+bias
  gemm128<4><<<dim3(8, 32), 512, 0, stream>>>(hbuf, outwt, (float*)d_out, 4096, 2048, 8192, 8192, abuf, out_b);
}